// Round 15
// baseline (239.271 us; speedup 1.0000x reference)
//
#include <hip/hip_runtime.h>
#include <math.h>

#define BB 2
#define HHH 56
#define WWW 56
#define CC 192
#define LL 3136
#define DI 384
#define KK 4
#define NN 16
#define RR 12
#define CP 44
#define HIDN 768
#define BL (BB*LL)
#define NCH 98   // chunks per sequence
#define CHL 32   // chunk length (98*32 = 3136)

typedef __attribute__((ext_vector_type(8))) short bf16x8;
typedef __attribute__((ext_vector_type(4))) float f32x4;

__device__ __forceinline__ float siluf_(float x){ return x/(1.f+__expf(-x)); }
__device__ __forceinline__ float geluf_(float x){ return 0.5f*x*(1.f+erff(x*0.70710678118654752f)); }
__device__ __forceinline__ unsigned short bf16r_(float x){
  unsigned int u = __float_as_uint(x);
  u += 0x7FFFu + ((u>>16)&1u);
  return (unsigned short)(u>>16);
}
__device__ __forceinline__ float bf2f_(unsigned short u){
  return __uint_as_float(((unsigned int)u)<<16);
}

// ---- weight fp32 -> bf16 convert (4 segments) + x_proj split prep, one launch ----
__global__ void k_prep(const float* __restrict__ s0, const float* __restrict__ s1,
                       const float* __restrict__ s2, const float* __restrict__ s3,
                       unsigned short* __restrict__ dst,
                       const float* __restrict__ xp, unsigned short* __restrict__ wXhi,
                       unsigned short* __restrict__ wXlo){
  if (blockIdx.x < 2016){
    int i = blockIdx.x*256 + threadIdx.x;
    if      (i < 147456) dst[i] = bf16r_(s0[i]);
    else if (i < 221184) dst[i] = bf16r_(s1[i-147456]);
    else if (i < 368640) dst[i] = bf16r_(s2[i-221184]);
    else if (i < 516096) dst[i] = bf16r_(s3[i-368640]);
  } else {
    int idx = (blockIdx.x-2016)*256 + threadIdx.x;
    if (idx >= 192*384) return;
    int row = idx / 384, d = idx % 384;
    int k = row / 48, j = row % 48;
    float v = 0.f;
    if (j < 12) v = xp[(k*CP + j)*DI + d];
    else if (j >= 16) v = xp[(k*CP + (j-4))*DI + d];
    unsigned short hi = bf16r_(v);
    wXhi[idx] = hi;
    wXlo[idx] = bf16r_(v - bf2f_(hi));
  }
}

// ---------------- depthwise 3x3 + residual (NHWC, C=192) ----------------
__global__ void k_dwconv_res(const float* __restrict__ in, const float* __restrict__ wgt,
                             const float* __restrict__ bias, float* __restrict__ out) {
  int idx = blockIdx.x*256 + threadIdx.x;
  const int total = BB*HHH*WWW*CC;
  if (idx >= total) return;
  int c = idx % CC;
  int w = (idx / CC) % WWW;
  int h = (idx / (CC*WWW)) % HHH;
  int b = idx / (CC*WWW*HHH);
  float acc = bias[c];
  #pragma unroll
  for (int kh=0; kh<3; kh++){
    int hh = h + kh - 1; if (hh < 0 || hh >= HHH) continue;
    #pragma unroll
    for (int kw=0; kw<3; kw++){
      int ww = w + kw - 1; if (ww < 0 || ww >= WWW) continue;
      acc += in[((b*HHH+hh)*WWW+ww)*CC + c] * wgt[c*9 + kh*3 + kw];
    }
  }
  out[idx] = in[idx] + acc;
}

// ---------------- LayerNorm over D=192, one wave per row, bf16 out ----------------
__global__ void k_ln192(const float* __restrict__ in, const float* __restrict__ g,
                        const float* __restrict__ bta, unsigned short* __restrict__ out, float eps) {
  int row = blockIdx.x*4 + (threadIdx.x>>6);
  int lane = threadIdx.x & 63;
  const float* p = in + (size_t)row*CC;
  float v0=p[lane], v1=p[lane+64], v2=p[lane+128];
  float s = v0+v1+v2, s2 = v0*v0+v1*v1+v2*v2;
  #pragma unroll
  for (int off=1; off<64; off<<=1){ s += __shfl_xor(s,off); s2 += __shfl_xor(s2,off); }
  float m = s*(1.f/192.f);
  float var = s2*(1.f/192.f) - m*m;
  float rstd = rsqrtf(var + eps);
  unsigned short* q = out + (size_t)row*CC;
  q[lane]     = bf16r_((v0-m)*rstd*g[lane]     + bta[lane]);
  q[lane+64]  = bf16r_((v1-m)*rstd*g[lane+64]  + bta[lane+64]);
  q[lane+128] = bf16r_((v2-m)*rstd*g[lane+128] + bta[lane+128]);
}

// ------- bf16 MFMA GEMM: out(MxN) = A(MxK)*W(NxK)^T; MT = M-tile (128 or 64) -------
enum { EPI_NONE=0, EPI_RES=1, EPI_BIAS_GELU=2, EPI_BIAS_RES=3 };

template<int MT, int EPI, int OUTBF>
__global__ __launch_bounds__(256) void k_gemm_mfma(const unsigned short* __restrict__ A,
      const unsigned short* __restrict__ W, const float* __restrict__ bias,
      const float* __restrict__ res, void* __restrict__ outp, int M, int Nn, int Kk) {
  __shared__ unsigned short As[MT][40];
  __shared__ unsigned short Bs[64][40];
  constexpr int NI = (MT==128) ? 4 : 2;
  int tid = threadIdx.x;
  int m0 = blockIdx.y*MT, n0 = blockIdx.x*64;
  int wid = tid>>6, lane = tid&63;
  int wm = (MT==128) ? wid*32 : (wid&1)*32;
  int wn = (MT==128) ? 0 : (wid>>1)*32;
  int fr = lane&15, fk = (lane>>4)*8;
  f32x4 acc[2][NI];
  #pragma unroll
  for (int i=0;i<2;i++)
    #pragma unroll
    for (int j=0;j<NI;j++) acc[i][j] = (f32x4){0.f,0.f,0.f,0.f};
  int arow, ak;
  if (MT==128){ arow = tid>>1; ak = (tid&1)*16; }
  else        { arow = tid>>2; ak = (tid&3)*8;  }
  int wrow = tid>>2, wk = (tid&3)*8;
  const unsigned short* Ap = A + (size_t)(m0+arow)*Kk + ak;
  const unsigned short* Wp = W + (size_t)(n0+wrow)*Kk + wk;
  for (int k0=0; k0<Kk; k0+=32){
    __syncthreads();
    if (MT==128){
      uint4 av0 = *(const uint4*)(Ap + k0);
      uint4 av1 = *(const uint4*)(Ap + k0 + 8);
      *(uint4*)&As[arow][ak]   = av0;
      *(uint4*)&As[arow][ak+8] = av1;
    } else {
      *(uint4*)&As[arow][ak] = *(const uint4*)(Ap + k0);
    }
    *(uint4*)&Bs[wrow][wk] = *(const uint4*)(Wp + k0);
    __syncthreads();
    bf16x8 af[2], bfr[NI];
    #pragma unroll
    for (int mi=0;mi<2;mi++) af[mi] = *(const bf16x8*)&As[wm + mi*16 + fr][fk];
    #pragma unroll
    for (int ni=0;ni<NI;ni++) bfr[ni] = *(const bf16x8*)&Bs[wn + ni*16 + fr][fk];
    #pragma unroll
    for (int mi=0;mi<2;mi++)
      #pragma unroll
      for (int ni=0;ni<NI;ni++)
        acc[mi][ni] = __builtin_amdgcn_mfma_f32_16x16x32_bf16(af[mi], bfr[ni], acc[mi][ni], 0,0,0);
  }
  int rbase = (lane>>4)*4;
  #pragma unroll
  for (int mi=0;mi<2;mi++){
    #pragma unroll
    for (int ni=0;ni<NI;ni++){
      int col = n0 + wn + ni*16 + fr;
      float bv = (EPI==EPI_BIAS_GELU || EPI==EPI_BIAS_RES) ? bias[col] : 0.f;
      #pragma unroll
      for (int r=0;r<4;r++){
        int row = m0 + wm + mi*16 + rbase + r;
        float v = acc[mi][ni][r] + bv;
        if (EPI==EPI_BIAS_GELU) v = geluf_(v);
        if (EPI==EPI_RES || EPI==EPI_BIAS_RES) v += res[(size_t)row*Nn + col];
        if (OUTBF) ((unsigned short*)outp)[(size_t)row*Nn + col] = bf16r_(v);
        else       ((float*)outp)[(size_t)row*Nn + col] = v;
      }
    }
  }
}

// ------- x_dbl split-bf16 GEMM: u_f32(BLx384) * wX(192x384)^T, scatter to records -------
__global__ __launch_bounds__(256) void k_xgemm(const float* __restrict__ uf,
      const unsigned short* __restrict__ wXhi, const unsigned short* __restrict__ wXlo,
      float* __restrict__ xdblT) {
  __shared__ unsigned short Ah[64][40];
  __shared__ unsigned short Al[64][40];
  __shared__ unsigned short Bh[64][40];
  __shared__ unsigned short Bl[64][40];
  int tid = threadIdx.x;
  int m0 = blockIdx.y*64, n0 = blockIdx.x*64;
  int wid = tid>>6, lane = tid&63;
  int fr = lane&15, fk = (lane>>4)*8;
  f32x4 acc[4];
  #pragma unroll
  for (int j=0;j<4;j++) acc[j] = (f32x4){0.f,0.f,0.f,0.f};
  int srow = tid>>2, sk = (tid&3)*8;
  const float* Ap = uf + (size_t)(m0+srow)*DI + sk;
  const unsigned short* Wh = wXhi + (size_t)(n0+srow)*DI + sk;
  const unsigned short* Wl = wXlo + (size_t)(n0+srow)*DI + sk;
  for (int k0=0; k0<DI; k0+=32){
    __syncthreads();
    float4 ua = *(const float4*)(Ap + k0);
    float4 ub = *(const float4*)(Ap + k0 + 4);
    uint4 wh = *(const uint4*)(Wh + k0);
    uint4 wl = *(const uint4*)(Wl + k0);
    float uv[8] = {ua.x,ua.y,ua.z,ua.w, ub.x,ub.y,ub.z,ub.w};
    #pragma unroll
    for (int j=0;j<8;j++){
      unsigned short hi = bf16r_(uv[j]);
      Ah[srow][sk+j] = hi;
      Al[srow][sk+j] = bf16r_(uv[j] - bf2f_(hi));
    }
    *(uint4*)&Bh[srow][sk] = wh;
    *(uint4*)&Bl[srow][sk] = wl;
    __syncthreads();
    bf16x8 ah = *(const bf16x8*)&Ah[wid*16 + fr][fk];
    bf16x8 al = *(const bf16x8*)&Al[wid*16 + fr][fk];
    #pragma unroll
    for (int ni=0;ni<4;ni++){
      bf16x8 bh = *(const bf16x8*)&Bh[ni*16 + fr][fk];
      bf16x8 bl = *(const bf16x8*)&Bl[ni*16 + fr][fk];
      acc[ni] = __builtin_amdgcn_mfma_f32_16x16x32_bf16(ah, bh, acc[ni], 0,0,0);
      acc[ni] = __builtin_amdgcn_mfma_f32_16x16x32_bf16(al, bh, acc[ni], 0,0,0);
      acc[ni] = __builtin_amdgcn_mfma_f32_16x16x32_bf16(ah, bl, acc[ni], 0,0,0);
    }
  }
  int rbase = (lane>>4)*4;
  #pragma unroll
  for (int ni=0;ni<4;ni++){
    int col = n0 + ni*16 + fr;
    int k = col / 48, j = col % 48;
    #pragma unroll
    for (int r=0;r<4;r++){
      int row = m0 + wid*16 + rbase + r;
      int b = row / LL, s = row % LL;
      int h = s / WWW, w2 = s % WWW;
      int l1 = w2*HHH + h;
      int lk = (k==0) ? s : (k==1) ? l1 : (k==2) ? (LL-1-s) : (LL-1-l1);
      xdblT[((size_t)((b*KK+k)*LL + lk))*48 + j] = acc[ni][r];
    }
  }
}

// ---- depthwise conv 3x3 + bias + SiLU -> fp32 u in both sequence layouts ----
__global__ void k_conv_xx(const float* __restrict__ xz, const float* __restrict__ cw,
                          const float* __restrict__ cb, float* __restrict__ xc0,
                          float* __restrict__ xc1) {
  int idx = blockIdx.x*256 + threadIdx.x;
  if (idx >= BB*LL*DI) return;
  int d = idx % DI;
  int l = (idx / DI) % LL;
  int b = idx / (DI*LL);
  int h = l / WWW, w = l % WWW;
  float acc = cb[d];
  #pragma unroll
  for (int kh=0; kh<3; kh++){
    int hh = h + kh - 1; if (hh < 0 || hh >= HHH) continue;
    #pragma unroll
    for (int kw=0; kw<3; kw++){
      int ww2 = w + kw - 1; if (ww2 < 0 || ww2 >= WWW) continue;
      acc += xz[((size_t)(b*LL + hh*WWW + ww2))*(2*DI) + d] * cw[d*9 + kh*3 + kw];
    }
  }
  float v = siluf_(acc);
  xc0[idx] = v;
  xc1[((size_t)(b*LL + w*HHH + h))*DI + d] = v;
}

// ======== chunked selective scan: single-wave blocks, LDS-staged records AND u ========
template<int PASS>
__global__ __launch_bounds__(64) void k_scan(const float* __restrict__ xc_l0,
        const float* __restrict__ xc_l1,
        const float* __restrict__ xdblT, const float* __restrict__ dtw, const float* __restrict__ dtb,
        const float* __restrict__ alogs, const float* __restrict__ Dsv,
        unsigned short* __restrict__ hend, float* __restrict__ sumdt, unsigned short* __restrict__ ysb) {
  __shared__ float recs[CHL*48];   // 6144 B: whole chunk's records
  __shared__ float us[CHL][64];    // 8192 B: whole chunk's u (per-lane)
  int ch = blockIdx.y, bk = blockIdx.z;
  int b = bk >> 2, k = bk & 3;
  int lane = threadIdx.x;
  int d = blockIdx.x*64 + lane;
  int kd = k*DI + d;
  const float* usrc = (k & 1) ? xc_l1 : xc_l0;
  bool rev = (k >= 2);
  // ---- stage records: 384 float4, coalesced, 6 per lane ----
  const float4* rg = (const float4*)(xdblT + ((size_t)bk*LL + ch*CHL)*48);
  float4* rs = (float4*)recs;
  #pragma unroll
  for (int j=0;j<6;j++) rs[lane + j*64] = rg[lane + j*64];
  // ---- stage u: 32 independent coalesced 256B loads ----
  #pragma unroll
  for (int j=0;j<CHL;j++){
    int li = ch*CHL + j;
    int lsrc = rev ? (LL-1-li) : li;
    us[j][lane] = usrc[((size_t)(b*LL + lsrc))*DI + d];
  }
  float w[12];
  #pragma unroll
  for (int r=0;r<12;r++) w[r] = dtw[kd*12 + r];
  float biasd = dtb[kd];
  float Dd = (PASS==1) ? Dsv[kd] : 0.f;
  float An2[16];
  #pragma unroll
  for (int n=0;n<16;n++) An2[n] = -__expf(alogs[kd*16 + n]) * 1.44269504f;
  bool pw = true;
  #pragma unroll
  for (int n=1;n<16;n++) pw = pw && (fabsf(An2[n] - (float)(n+1)*An2[0]) <= 1e-3f*(float)(n+1)*fabsf(An2[0]));
  float h[16];
  size_t hb = ((size_t)(bk*NCH + ch)*DI + d)*16;
  if (PASS==0){
    #pragma unroll
    for (int n=0;n<16;n++) h[n]=0.f;
  } else {
    uint4 q0 = *(const uint4*)&hend[hb];
    uint4 q1 = *(const uint4*)&hend[hb+8];
    unsigned int qa[8] = {q0.x,q0.y,q0.z,q0.w, q1.x,q1.y,q1.z,q1.w};
    #pragma unroll
    for (int j=0;j<8;j++){
      h[2*j]   = bf2f_((unsigned short)(qa[j] & 0xffffu));
      h[2*j+1] = bf2f_((unsigned short)(qa[j] >> 16));
    }
  }
  __syncthreads();   // records + u staged
  float cum = 0.f;
  #pragma unroll 2
  for (int i=0;i<CHL;i++){
    int li = ch*CHL + i;
    float uu = us[i][lane];
    const float* rec = recs + i*48;
    float4 t0 = *(const float4*)(rec);
    float4 t1 = *(const float4*)(rec+4);
    float4 t2 = *(const float4*)(rec+8);
    float4 B0 = *(const float4*)(rec+16);
    float4 B1 = *(const float4*)(rec+20);
    float4 B2 = *(const float4*)(rec+24);
    float4 B3 = *(const float4*)(rec+28);
    float a0 = fmaf(t0.x,w[0], fmaf(t0.y,w[1], fmaf(t0.z,w[2], t0.w*w[3])));
    float a1 = fmaf(t1.x,w[4], fmaf(t1.y,w[5], fmaf(t1.z,w[6], t1.w*w[7])));
    float a2 = fmaf(t2.x,w[8], fmaf(t2.y,w[9], fmaf(t2.z,w[10], t2.w*w[11])));
    float a = biasd + a0 + (a1 + a2);
    float dt = 0.69314718f * log2f(1.f + exp2f(a*1.44269504f));
    float dtu = dt*uu;
    if (PASS==0) cum += dt;
    float dA[16];
    if (pw){
      float r1 = exp2f(dt*An2[0]);
      float r2 = r1*r1;
      float r3 = r2*r1;
      float r4 = r2*r2;
      float r8 = r4*r4;
      dA[0]=r1;     dA[1]=r2;     dA[2]=r3;     dA[3]=r4;
      dA[4]=r4*r1;  dA[5]=r4*r2;  dA[6]=r4*r3;  dA[7]=r8;
      dA[8]=r8*r1;  dA[9]=r8*r2;  dA[10]=r8*r3; dA[11]=r8*r4;
      dA[12]=r8*dA[4]; dA[13]=r8*dA[5]; dA[14]=r8*dA[6]; dA[15]=r8*r8;
    } else {
      #pragma unroll
      for (int n=0;n<16;n++) dA[n] = exp2f(dt*An2[n]);
    }
    float Bv[16] = {B0.x,B0.y,B0.z,B0.w, B1.x,B1.y,B1.z,B1.w,
                    B2.x,B2.y,B2.z,B2.w, B3.x,B3.y,B3.z,B3.w};
    #pragma unroll
    for (int n=0;n<16;n++) h[n] = fmaf(dA[n], h[n], dtu*Bv[n]);
    if (PASS==1){
      float4 C0 = *(const float4*)(rec+32);
      float4 C1 = *(const float4*)(rec+36);
      float4 C2 = *(const float4*)(rec+40);
      float4 C3 = *(const float4*)(rec+44);
      float y0 = fmaf(h[0], C0.x, fmaf(h[1], C0.y, fmaf(h[2], C0.z, h[3]*C0.w)));
      float y1 = fmaf(h[4], C1.x, fmaf(h[5], C1.y, fmaf(h[6], C1.z, h[7]*C1.w)));
      float y2 = fmaf(h[8], C2.x, fmaf(h[9], C2.y, fmaf(h[10],C2.z, h[11]*C2.w)));
      float y3 = fmaf(h[12],C3.x, fmaf(h[13],C3.y, fmaf(h[14],C3.z, h[15]*C3.w)));
      float y = fmaf(uu, Dd, (y0+y1)+(y2+y3));
      ysb[((size_t)(bk*LL + li))*DI + d] = bf16r_(y);
    }
  }
  if (PASS==0){
    unsigned int pk[8];
    #pragma unroll
    for (int j=0;j<8;j++)
      pk[j] = ((unsigned int)bf16r_(h[2*j+1])<<16) | (unsigned int)bf16r_(h[2*j]);
    *(uint4*)&hend[hb]   = make_uint4(pk[0],pk[1],pk[2],pk[3]);
    *(uint4*)&hend[hb+8] = make_uint4(pk[4],pk[5],pk[6],pk[7]);
    sumdt[(bk*NCH + ch)*DI + d] = cum;
  }
}

// S2: per (b,k,4d-block) wave: prefix over chunks; hend[c] <- incoming state H_{c-1} (bf16)
__global__ __launch_bounds__(64) void k_scanmid(const float* __restrict__ alogs,
        const float* __restrict__ sumdt, unsigned short* __restrict__ hend) {
  int bid = blockIdx.x;
  int dblk = bid % 96;
  int k = (bid/96) % KK;
  int b = bid/(96*KK);
  int lane = threadIdx.x;
  int d4 = lane>>4, n = lane&15;
  int d = dblk*4 + d4;
  int bk = b*KK + k;
  float Ac2 = -__expf(alogs[(k*DI+d)*16 + n]) * 1.44269504f;
  float H = 0.f;
  for (int c=0;c<NCH;c++){
    float sdt = sumdt[(bk*NCH + c)*DI + d];
    float aexp = exp2f(Ac2 * sdt);
    size_t idx = ((size_t)(bk*NCH + c)*DI + dblk*4)*16 + lane;
    float tmp = bf2f_(hend[idx]);
    hend[idx] = bf16r_(H);
    H = fmaf(aexp, H, tmp);
  }
}

// ---------------- fused combine + LN(Di) + silu(z) gate -> a2 (B,L,Di) bf16 ----------------
__global__ __launch_bounds__(384) void k_fuse(const unsigned short* __restrict__ ysb,
      const float* __restrict__ xz, const float* __restrict__ og, const float* __restrict__ ob,
      unsigned short* __restrict__ a2) {
  __shared__ float sa[6], sb[6];
  int b = blockIdx.x / LL, l = blockIdx.x % LL;
  int d = threadIdx.x;
  int h_ = l / WWW, w_ = l % WWW;
  int l1 = w_*HHH + h_;
  float y = bf2f_(ysb[((size_t)((b*KK+0)*LL + l))*DI + d])
          + bf2f_(ysb[((size_t)((b*KK+1)*LL + l1))*DI + d])
          + bf2f_(ysb[((size_t)((b*KK+2)*LL + (LL-1-l)))*DI + d])
          + bf2f_(ysb[((size_t)((b*KK+3)*LL + (LL-1-l1)))*DI + d]);
  float s = y, s2 = y*y;
  #pragma unroll
  for (int off=1; off<64; off<<=1){ s += __shfl_xor(s,off); s2 += __shfl_xor(s2,off); }
  int wid = d >> 6;
  if ((d & 63) == 0){ sa[wid] = s; sb[wid] = s2; }
  __syncthreads();
  s = sa[0]+sa[1]+sa[2]+sa[3]+sa[4]+sa[5];
  s2 = sb[0]+sb[1]+sb[2]+sb[3]+sb[4]+sb[5];
  float m = s*(1.f/DI);
  float var = s2*(1.f/DI) - m*m;
  float rstd = rsqrtf(var + 1e-5f);
  float v = (y - m)*rstd*og[d] + ob[d];
  float z = xz[((size_t)(b*LL + l))*(2*DI) + DI + d];
  a2[((size_t)(b*LL + l))*DI + d] = bf16r_(v * siluf_(z));
}

extern "C" void kernel_launch(void* const* d_in, const int* in_sizes, int n_in,
                              void* d_out, int out_size, void* d_ws, size_t ws_size,
                              hipStream_t stream) {
  (void)in_sizes; (void)n_in; (void)out_size; (void)ws_size;
  const float* x       = (const float*)d_in[0];
  const float* cpe1_w  = (const float*)d_in[1];
  const float* cpe1_b  = (const float*)d_in[2];
  const float* ln1_g   = (const float*)d_in[3];
  const float* ln1_b   = (const float*)d_in[4];
  const float* in_proj = (const float*)d_in[5];
  const float* conv_w  = (const float*)d_in[6];
  const float* conv_b  = (const float*)d_in[7];
  const float* x_proj  = (const float*)d_in[8];
  const float* dt_w    = (const float*)d_in[9];
  const float* dt_b    = (const float*)d_in[10];
  const float* A_logs  = (const float*)d_in[11];
  const float* Dsv     = (const float*)d_in[12];
  const float* onorm_g = (const float*)d_in[13];
  const float* onorm_b = (const float*)d_in[14];
  const float* out_proj= (const float*)d_in[15];
  const float* cpe2_w  = (const float*)d_in[16];
  const float* cpe2_b  = (const float*)d_in[17];
  const float* ln2_g   = (const float*)d_in[18];
  const float* ln2_b   = (const float*)d_in[19];
  const float* fc1_w   = (const float*)d_in[20];
  const float* fc1_b   = (const float*)d_in[21];
  const float* fc2_w   = (const float*)d_in[22];
  const float* fc2_b   = (const float*)d_in[23];
  float* out = (float*)d_out;
  float* wsf = (float*)d_ws;

  float* x1    = wsf;                        // 1,204,224 f
  float* xlnf  = x1 + 1204224;               // 1,204,224 f
  float* xz    = xlnf + 1204224;             // 4,816,896 f
  float* xc_l0 = xz + 4816896;               // 2,408,448 f  (B,L,Di) fp32
  float* xc_l1 = xc_l0 + 2408448;            // 2,408,448 f  (B,L1,Di) fp32
  float* ysbf  = xc_l1 + 2408448;            // 4,816,896 f = 9,633,792 bf16 (bk,L,Di)
  float* hendf = ysbf + 4816896;             // 2,408,448 f = 4,816,896 bf16 (bk,NCH,Di,16)
  float* sumdt = hendf + 2408448;            // 301,056 f
  float* xdblT = sumdt + 301056;             // 1,204,224 f
  unsigned short* wbf = (unsigned short*)(xdblT + 1204224); // 516,096 bf16
  unsigned short* wXhi = wbf + 516096;       // 73,728 bf16
  unsigned short* wXlo = wXhi + 73728;       // 73,728 bf16
  // aliases (lifetime-disjoint)
  unsigned short* xln  = (unsigned short*)xlnf;
  unsigned short* xln2 = (unsigned short*)xlnf;
  unsigned short* ysb  = (unsigned short*)ysbf;
  unsigned short* hend = (unsigned short*)hendf;
  unsigned short* a2   = (unsigned short*)xdblT;  // after scan2
  float* x2   = xc_l0;                            // after k_fuse
  float* x3   = xz;                               // after k_fuse
  unsigned short* hbuf = (unsigned short*)ysbf;   // after k_fuse
  unsigned short* wIn  = wbf;
  unsigned short* wOut = wbf + 147456;
  unsigned short* wF1  = wbf + 221184;
  unsigned short* wF2  = wbf + 368640;

  k_prep<<<2016+288, 256, 0, stream>>>(in_proj, out_proj, fc1_w, fc2_w, wbf, x_proj, wXhi, wXlo);
  k_dwconv_res<<<(BB*HHH*WWW*CC+255)/256, 256, 0, stream>>>(x, cpe1_w, cpe1_b, x1);
  k_ln192<<<BL/4, 256, 0, stream>>>(x1, ln1_g, ln1_b, xln, 1e-6f);
  k_gemm_mfma<128,EPI_NONE,0><<<dim3(768/64, BL/128), 256, 0, stream>>>(xln, wIn, nullptr, nullptr, xz, BL, 2*DI, CC);
  k_conv_xx<<<(BB*LL*DI+255)/256, 256, 0, stream>>>(xz, conv_w, conv_b, xc_l0, xc_l1);
  k_xgemm<<<dim3(3, BL/64), 256, 0, stream>>>(xc_l0, wXhi, wXlo, xdblT);
  k_scan<0><<<dim3(6, NCH, BB*KK), 64, 0, stream>>>(xc_l0, xc_l1, xdblT, dt_w, dt_b, A_logs, Dsv, hend, sumdt, ysb);
  k_scanmid<<<BB*KK*96, 64, 0, stream>>>(A_logs, sumdt, hend);
  k_scan<1><<<dim3(6, NCH, BB*KK), 64, 0, stream>>>(xc_l0, xc_l1, xdblT, dt_w, dt_b, A_logs, Dsv, hend, sumdt, ysb);
  k_fuse<<<BB*LL, 384, 0, stream>>>(ysb, xz, onorm_g, onorm_b, a2);
  k_gemm_mfma<64,EPI_RES,0><<<dim3(192/64, BL/64), 256, 0, stream>>>(a2, wOut, nullptr, x1, x2, BL, CC, DI);
  k_dwconv_res<<<(BB*HHH*WWW*CC+255)/256, 256, 0, stream>>>(x2, cpe2_w, cpe2_b, x3);
  k_ln192<<<BL/4, 256, 0, stream>>>(x3, ln2_g, ln2_b, xln2, 1e-6f);
  k_gemm_mfma<128,EPI_BIAS_GELU,1><<<dim3(768/64, BL/128), 256, 0, stream>>>(xln2, wF1, fc1_b, nullptr, hbuf, BL, HIDN, CC);
  k_gemm_mfma<64,EPI_BIAS_RES,0><<<dim3(192/64, BL/64), 256, 0, stream>>>(hbuf, wF2, fc2_b, x3, out, BL, CC, HIDN);
}

// Round 16
// 217.081 us; speedup vs baseline: 1.1022x; 1.1022x over previous
//
#include <hip/hip_runtime.h>
#include <math.h>

#define BB 2
#define HHH 56
#define WWW 56
#define CC 192
#define LL 3136
#define DI 384
#define KK 4
#define NN 16
#define RR 12
#define CP 44
#define HIDN 768
#define BL (BB*LL)
#define NCH 98   // chunks per sequence
#define CHL 32   // chunk length (98*32 = 3136)

typedef __attribute__((ext_vector_type(8))) short bf16x8;
typedef __attribute__((ext_vector_type(4))) float f32x4;

__device__ __forceinline__ float siluf_(float x){ return x/(1.f+__expf(-x)); }
__device__ __forceinline__ float geluf_(float x){ return 0.5f*x*(1.f+erff(x*0.70710678118654752f)); }
__device__ __forceinline__ unsigned short bf16r_(float x){
  unsigned int u = __float_as_uint(x);
  u += 0x7FFFu + ((u>>16)&1u);
  return (unsigned short)(u>>16);
}
__device__ __forceinline__ float bf2f_(unsigned short u){
  return __uint_as_float(((unsigned int)u)<<16);
}

// ---- weight fp32 -> bf16 convert (4 segments) + x_proj split prep, one launch ----
__global__ void k_prep(const float* __restrict__ s0, const float* __restrict__ s1,
                       const float* __restrict__ s2, const float* __restrict__ s3,
                       unsigned short* __restrict__ dst,
                       const float* __restrict__ xp, unsigned short* __restrict__ wXhi,
                       unsigned short* __restrict__ wXlo){
  if (blockIdx.x < 2016){
    int i = blockIdx.x*256 + threadIdx.x;
    if      (i < 147456) dst[i] = bf16r_(s0[i]);
    else if (i < 221184) dst[i] = bf16r_(s1[i-147456]);
    else if (i < 368640) dst[i] = bf16r_(s2[i-221184]);
    else if (i < 516096) dst[i] = bf16r_(s3[i-368640]);
  } else {
    int idx = (blockIdx.x-2016)*256 + threadIdx.x;
    if (idx >= 192*384) return;
    int row = idx / 384, d = idx % 384;
    int k = row / 48, j = row % 48;
    float v = 0.f;
    if (j < 12) v = xp[(k*CP + j)*DI + d];
    else if (j >= 16) v = xp[(k*CP + (j-4))*DI + d];
    unsigned short hi = bf16r_(v);
    wXhi[idx] = hi;
    wXlo[idx] = bf16r_(v - bf2f_(hi));
  }
}

// ---- fused depthwise 3x3 + residual + LayerNorm(192): one block per pixel ----
__global__ __launch_bounds__(192) void k_dwln(const float* __restrict__ in,
      const float* __restrict__ wgt, const float* __restrict__ bias,
      const float* __restrict__ g, const float* __restrict__ bta,
      float* __restrict__ xout, unsigned short* __restrict__ lnout, float eps) {
  __shared__ float sa[3], sb[3];
  int pix = blockIdx.x;
  int c = threadIdx.x;
  int w = pix % WWW, h = (pix/WWW) % HHH, b = pix/(WWW*HHH);
  float acc = bias[c];
  #pragma unroll
  for (int kh=0; kh<3; kh++){
    int hh = h + kh - 1; if (hh < 0 || hh >= HHH) continue;
    #pragma unroll
    for (int kw=0; kw<3; kw++){
      int ww = w + kw - 1; if (ww < 0 || ww >= WWW) continue;
      acc += in[((b*HHH+hh)*WWW+ww)*CC + c] * wgt[c*9 + kh*3 + kw];
    }
  }
  float v = in[(size_t)pix*CC + c] + acc;
  xout[(size_t)pix*CC + c] = v;
  float s = v, s2 = v*v;
  #pragma unroll
  for (int off=1; off<64; off<<=1){ s += __shfl_xor(s,off); s2 += __shfl_xor(s2,off); }
  int wv = c >> 6;
  if ((c & 63) == 0){ sa[wv] = s; sb[wv] = s2; }
  __syncthreads();
  s = sa[0]+sa[1]+sa[2];
  s2 = sb[0]+sb[1]+sb[2];
  float m = s*(1.f/192.f);
  float var = s2*(1.f/192.f) - m*m;
  float rstd = rsqrtf(var + eps);
  lnout[(size_t)pix*CC + c] = bf16r_((v-m)*rstd*g[c] + bta[c]);
}

// ------- bf16 MFMA GEMM: out(MxN) = A(MxK)*W(NxK)^T; MT = M-tile (128 or 64) -------
enum { EPI_NONE=0, EPI_RES=1, EPI_BIAS_GELU=2, EPI_BIAS_RES=3 };

template<int MT, int EPI, int OUTBF>
__global__ __launch_bounds__(256) void k_gemm_mfma(const unsigned short* __restrict__ A,
      const unsigned short* __restrict__ W, const float* __restrict__ bias,
      const float* __restrict__ res, void* __restrict__ outp, int M, int Nn, int Kk) {
  __shared__ unsigned short As[MT][40];
  __shared__ unsigned short Bs[64][40];
  constexpr int NI = (MT==128) ? 4 : 2;
  int tid = threadIdx.x;
  int m0 = blockIdx.y*MT, n0 = blockIdx.x*64;
  int wid = tid>>6, lane = tid&63;
  int wm = (MT==128) ? wid*32 : (wid&1)*32;
  int wn = (MT==128) ? 0 : (wid>>1)*32;
  int fr = lane&15, fk = (lane>>4)*8;
  f32x4 acc[2][NI];
  #pragma unroll
  for (int i=0;i<2;i++)
    #pragma unroll
    for (int j=0;j<NI;j++) acc[i][j] = (f32x4){0.f,0.f,0.f,0.f};
  int arow, ak;
  if (MT==128){ arow = tid>>1; ak = (tid&1)*16; }
  else        { arow = tid>>2; ak = (tid&3)*8;  }
  int wrow = tid>>2, wk = (tid&3)*8;
  const unsigned short* Ap = A + (size_t)(m0+arow)*Kk + ak;
  const unsigned short* Wp = W + (size_t)(n0+wrow)*Kk + wk;
  for (int k0=0; k0<Kk; k0+=32){
    __syncthreads();
    if (MT==128){
      uint4 av0 = *(const uint4*)(Ap + k0);
      uint4 av1 = *(const uint4*)(Ap + k0 + 8);
      *(uint4*)&As[arow][ak]   = av0;
      *(uint4*)&As[arow][ak+8] = av1;
    } else {
      *(uint4*)&As[arow][ak] = *(const uint4*)(Ap + k0);
    }
    *(uint4*)&Bs[wrow][wk] = *(const uint4*)(Wp + k0);
    __syncthreads();
    bf16x8 af[2], bfr[NI];
    #pragma unroll
    for (int mi=0;mi<2;mi++) af[mi] = *(const bf16x8*)&As[wm + mi*16 + fr][fk];
    #pragma unroll
    for (int ni=0;ni<NI;ni++) bfr[ni] = *(const bf16x8*)&Bs[wn + ni*16 + fr][fk];
    #pragma unroll
    for (int mi=0;mi<2;mi++)
      #pragma unroll
      for (int ni=0;ni<NI;ni++)
        acc[mi][ni] = __builtin_amdgcn_mfma_f32_16x16x32_bf16(af[mi], bfr[ni], acc[mi][ni], 0,0,0);
  }
  int rbase = (lane>>4)*4;
  #pragma unroll
  for (int mi=0;mi<2;mi++){
    #pragma unroll
    for (int ni=0;ni<NI;ni++){
      int col = n0 + wn + ni*16 + fr;
      float bv = (EPI==EPI_BIAS_GELU || EPI==EPI_BIAS_RES) ? bias[col] : 0.f;
      #pragma unroll
      for (int r=0;r<4;r++){
        int row = m0 + wm + mi*16 + rbase + r;
        float v = acc[mi][ni][r] + bv;
        if (EPI==EPI_BIAS_GELU) v = geluf_(v);
        if (EPI==EPI_RES || EPI==EPI_BIAS_RES) v += res[(size_t)row*Nn + col];
        if (OUTBF) ((unsigned short*)outp)[(size_t)row*Nn + col] = bf16r_(v);
        else       ((float*)outp)[(size_t)row*Nn + col] = v;
      }
    }
  }
}

// ------- x_dbl split-bf16 GEMM: u_f32(BLx384) * wX(192x384)^T, scatter to records -------
__global__ __launch_bounds__(256) void k_xgemm(const float* __restrict__ uf,
      const unsigned short* __restrict__ wXhi, const unsigned short* __restrict__ wXlo,
      float* __restrict__ xdblT) {
  __shared__ unsigned short Ah[64][40];
  __shared__ unsigned short Al[64][40];
  __shared__ unsigned short Bh[64][40];
  __shared__ unsigned short Bl[64][40];
  int tid = threadIdx.x;
  int m0 = blockIdx.y*64, n0 = blockIdx.x*64;
  int wid = tid>>6, lane = tid&63;
  int fr = lane&15, fk = (lane>>4)*8;
  f32x4 acc[4];
  #pragma unroll
  for (int j=0;j<4;j++) acc[j] = (f32x4){0.f,0.f,0.f,0.f};
  int srow = tid>>2, sk = (tid&3)*8;
  const float* Ap = uf + (size_t)(m0+srow)*DI + sk;
  const unsigned short* Wh = wXhi + (size_t)(n0+srow)*DI + sk;
  const unsigned short* Wl = wXlo + (size_t)(n0+srow)*DI + sk;
  for (int k0=0; k0<DI; k0+=32){
    __syncthreads();
    float4 ua = *(const float4*)(Ap + k0);
    float4 ub = *(const float4*)(Ap + k0 + 4);
    uint4 wh = *(const uint4*)(Wh + k0);
    uint4 wl = *(const uint4*)(Wl + k0);
    float uv[8] = {ua.x,ua.y,ua.z,ua.w, ub.x,ub.y,ub.z,ub.w};
    #pragma unroll
    for (int j=0;j<8;j++){
      unsigned short hi = bf16r_(uv[j]);
      Ah[srow][sk+j] = hi;
      Al[srow][sk+j] = bf16r_(uv[j] - bf2f_(hi));
    }
    *(uint4*)&Bh[srow][sk] = wh;
    *(uint4*)&Bl[srow][sk] = wl;
    __syncthreads();
    bf16x8 ah = *(const bf16x8*)&Ah[wid*16 + fr][fk];
    bf16x8 al = *(const bf16x8*)&Al[wid*16 + fr][fk];
    #pragma unroll
    for (int ni=0;ni<4;ni++){
      bf16x8 bh = *(const bf16x8*)&Bh[ni*16 + fr][fk];
      bf16x8 bl = *(const bf16x8*)&Bl[ni*16 + fr][fk];
      acc[ni] = __builtin_amdgcn_mfma_f32_16x16x32_bf16(ah, bh, acc[ni], 0,0,0);
      acc[ni] = __builtin_amdgcn_mfma_f32_16x16x32_bf16(al, bh, acc[ni], 0,0,0);
      acc[ni] = __builtin_amdgcn_mfma_f32_16x16x32_bf16(ah, bl, acc[ni], 0,0,0);
    }
  }
  int rbase = (lane>>4)*4;
  #pragma unroll
  for (int ni=0;ni<4;ni++){
    int col = n0 + ni*16 + fr;
    int k = col / 48, j = col % 48;
    #pragma unroll
    for (int r=0;r<4;r++){
      int row = m0 + wid*16 + rbase + r;
      int b = row / LL, s = row % LL;
      int h = s / WWW, w2 = s % WWW;
      int l1 = w2*HHH + h;
      int lk = (k==0) ? s : (k==1) ? l1 : (k==2) ? (LL-1-s) : (LL-1-l1);
      xdblT[((size_t)((b*KK+k)*LL + lk))*48 + j] = acc[ni][r];
    }
  }
}

// ---- depthwise conv 3x3 + bias + SiLU -> fp32 u in both sequence layouts ----
__global__ void k_conv_xx(const float* __restrict__ xz, const float* __restrict__ cw,
                          const float* __restrict__ cb, float* __restrict__ xc0,
                          float* __restrict__ xc1) {
  int idx = blockIdx.x*256 + threadIdx.x;
  if (idx >= BB*LL*DI) return;
  int d = idx % DI;
  int l = (idx / DI) % LL;
  int b = idx / (DI*LL);
  int h = l / WWW, w = l % WWW;
  float acc = cb[d];
  #pragma unroll
  for (int kh=0; kh<3; kh++){
    int hh = h + kh - 1; if (hh < 0 || hh >= HHH) continue;
    #pragma unroll
    for (int kw=0; kw<3; kw++){
      int ww2 = w + kw - 1; if (ww2 < 0 || ww2 >= WWW) continue;
      acc += xz[((size_t)(b*LL + hh*WWW + ww2))*(2*DI) + d] * cw[d*9 + kh*3 + kw];
    }
  }
  float v = siluf_(acc);
  xc0[idx] = v;
  xc1[((size_t)(b*LL + w*HHH + h))*DI + d] = v;
}

// ======== chunked selective scan: single-wave blocks, LDS-staged records (r13 form) ========
template<int PASS>
__global__ __launch_bounds__(64) void k_scan(const float* __restrict__ xc_l0,
        const float* __restrict__ xc_l1,
        const float* __restrict__ xdblT, const float* __restrict__ dtw, const float* __restrict__ dtb,
        const float* __restrict__ alogs, const float* __restrict__ Dsv,
        unsigned short* __restrict__ hend, float* __restrict__ sumdt, unsigned short* __restrict__ ysb) {
  __shared__ float recs[CHL*48];   // 6144 B: whole chunk's records
  int ch = blockIdx.y, bk = blockIdx.z;
  int b = bk >> 2, k = bk & 3;
  int lane = threadIdx.x;
  int d = blockIdx.x*64 + lane;
  int kd = k*DI + d;
  const float4* rg = (const float4*)(xdblT + ((size_t)bk*LL + ch*CHL)*48);
  float4* rs = (float4*)recs;
  #pragma unroll
  for (int j=0;j<6;j++) rs[lane + j*64] = rg[lane + j*64];
  float w[12];
  #pragma unroll
  for (int r=0;r<12;r++) w[r] = dtw[kd*12 + r];
  float biasd = dtb[kd];
  float Dd = (PASS==1) ? Dsv[kd] : 0.f;
  float An2[16];
  #pragma unroll
  for (int n=0;n<16;n++) An2[n] = -__expf(alogs[kd*16 + n]) * 1.44269504f;
  bool pw = true;
  #pragma unroll
  for (int n=1;n<16;n++) pw = pw && (fabsf(An2[n] - (float)(n+1)*An2[0]) <= 1e-3f*(float)(n+1)*fabsf(An2[0]));
  const float* usrc = (k & 1) ? xc_l1 : xc_l0;
  bool rev = (k >= 2);
  float h[16];
  size_t hb = ((size_t)(bk*NCH + ch)*DI + d)*16;
  if (PASS==0){
    #pragma unroll
    for (int n=0;n<16;n++) h[n]=0.f;
  } else {
    uint4 q0 = *(const uint4*)&hend[hb];
    uint4 q1 = *(const uint4*)&hend[hb+8];
    unsigned int qa[8] = {q0.x,q0.y,q0.z,q0.w, q1.x,q1.y,q1.z,q1.w};
    #pragma unroll
    for (int j=0;j<8;j++){
      h[2*j]   = bf2f_((unsigned short)(qa[j] & 0xffffu));
      h[2*j+1] = bf2f_((unsigned short)(qa[j] >> 16));
    }
  }
  __syncthreads();   // records staged
  float cum = 0.f;
  #pragma unroll 2
  for (int i=0;i<CHL;i++){
    int li = ch*CHL + i;
    int lsrc = rev ? (LL-1-li) : li;
    float uu = usrc[((size_t)(b*LL + lsrc))*DI + d];
    const float* rec = recs + i*48;
    float4 t0 = *(const float4*)(rec);
    float4 t1 = *(const float4*)(rec+4);
    float4 t2 = *(const float4*)(rec+8);
    float4 B0 = *(const float4*)(rec+16);
    float4 B1 = *(const float4*)(rec+20);
    float4 B2 = *(const float4*)(rec+24);
    float4 B3 = *(const float4*)(rec+28);
    float a0 = fmaf(t0.x,w[0], fmaf(t0.y,w[1], fmaf(t0.z,w[2], t0.w*w[3])));
    float a1 = fmaf(t1.x,w[4], fmaf(t1.y,w[5], fmaf(t1.z,w[6], t1.w*w[7])));
    float a2 = fmaf(t2.x,w[8], fmaf(t2.y,w[9], fmaf(t2.z,w[10], t2.w*w[11])));
    float a = biasd + a0 + (a1 + a2);
    float dt = 0.69314718f * log2f(1.f + exp2f(a*1.44269504f));
    float dtu = dt*uu;
    if (PASS==0) cum += dt;
    float dA[16];
    if (pw){
      float r1 = exp2f(dt*An2[0]);
      float r2 = r1*r1;
      float r3 = r2*r1;
      float r4 = r2*r2;
      float r8 = r4*r4;
      dA[0]=r1;     dA[1]=r2;     dA[2]=r3;     dA[3]=r4;
      dA[4]=r4*r1;  dA[5]=r4*r2;  dA[6]=r4*r3;  dA[7]=r8;
      dA[8]=r8*r1;  dA[9]=r8*r2;  dA[10]=r8*r3; dA[11]=r8*r4;
      dA[12]=r8*dA[4]; dA[13]=r8*dA[5]; dA[14]=r8*dA[6]; dA[15]=r8*r8;
    } else {
      #pragma unroll
      for (int n=0;n<16;n++) dA[n] = exp2f(dt*An2[n]);
    }
    float Bv[16] = {B0.x,B0.y,B0.z,B0.w, B1.x,B1.y,B1.z,B1.w,
                    B2.x,B2.y,B2.z,B2.w, B3.x,B3.y,B3.z,B3.w};
    #pragma unroll
    for (int n=0;n<16;n++) h[n] = fmaf(dA[n], h[n], dtu*Bv[n]);
    if (PASS==1){
      float4 C0 = *(const float4*)(rec+32);
      float4 C1 = *(const float4*)(rec+36);
      float4 C2 = *(const float4*)(rec+40);
      float4 C3 = *(const float4*)(rec+44);
      float y0 = fmaf(h[0], C0.x, fmaf(h[1], C0.y, fmaf(h[2], C0.z, h[3]*C0.w)));
      float y1 = fmaf(h[4], C1.x, fmaf(h[5], C1.y, fmaf(h[6], C1.z, h[7]*C1.w)));
      float y2 = fmaf(h[8], C2.x, fmaf(h[9], C2.y, fmaf(h[10],C2.z, h[11]*C2.w)));
      float y3 = fmaf(h[12],C3.x, fmaf(h[13],C3.y, fmaf(h[14],C3.z, h[15]*C3.w)));
      float y = fmaf(uu, Dd, (y0+y1)+(y2+y3));
      ysb[((size_t)(bk*LL + li))*DI + d] = bf16r_(y);
    }
  }
  if (PASS==0){
    unsigned int pk[8];
    #pragma unroll
    for (int j=0;j<8;j++)
      pk[j] = ((unsigned int)bf16r_(h[2*j+1])<<16) | (unsigned int)bf16r_(h[2*j]);
    *(uint4*)&hend[hb]   = make_uint4(pk[0],pk[1],pk[2],pk[3]);
    *(uint4*)&hend[hb+8] = make_uint4(pk[4],pk[5],pk[6],pk[7]);
    sumdt[(bk*NCH + ch)*DI + d] = cum;
  }
}

// S2: per (b,k,4d-block) wave: prefix over chunks; hend[c] <- incoming state H_{c-1} (bf16)
__global__ __launch_bounds__(64) void k_scanmid(const float* __restrict__ alogs,
        const float* __restrict__ sumdt, unsigned short* __restrict__ hend) {
  int bid = blockIdx.x;
  int dblk = bid % 96;
  int k = (bid/96) % KK;
  int b = bid/(96*KK);
  int lane = threadIdx.x;
  int d4 = lane>>4, n = lane&15;
  int d = dblk*4 + d4;
  int bk = b*KK + k;
  float Ac2 = -__expf(alogs[(k*DI+d)*16 + n]) * 1.44269504f;
  float H = 0.f;
  for (int c=0;c<NCH;c++){
    float sdt = sumdt[(bk*NCH + c)*DI + d];
    float aexp = exp2f(Ac2 * sdt);
    size_t idx = ((size_t)(bk*NCH + c)*DI + dblk*4)*16 + lane;
    float tmp = bf2f_(hend[idx]);
    hend[idx] = bf16r_(H);
    H = fmaf(aexp, H, tmp);
  }
}

// ---------------- fused combine + LN(Di) + silu(z) gate -> a2 (B,L,Di) bf16 ----------------
__global__ __launch_bounds__(384) void k_fuse(const unsigned short* __restrict__ ysb,
      const float* __restrict__ xz, const float* __restrict__ og, const float* __restrict__ ob,
      unsigned short* __restrict__ a2) {
  __shared__ float sa[6], sb[6];
  int b = blockIdx.x / LL, l = blockIdx.x % LL;
  int d = threadIdx.x;
  int h_ = l / WWW, w_ = l % WWW;
  int l1 = w_*HHH + h_;
  float y = bf2f_(ysb[((size_t)((b*KK+0)*LL + l))*DI + d])
          + bf2f_(ysb[((size_t)((b*KK+1)*LL + l1))*DI + d])
          + bf2f_(ysb[((size_t)((b*KK+2)*LL + (LL-1-l)))*DI + d])
          + bf2f_(ysb[((size_t)((b*KK+3)*LL + (LL-1-l1)))*DI + d]);
  float s = y, s2 = y*y;
  #pragma unroll
  for (int off=1; off<64; off<<=1){ s += __shfl_xor(s,off); s2 += __shfl_xor(s2,off); }
  int wid = d >> 6;
  if ((d & 63) == 0){ sa[wid] = s; sb[wid] = s2; }
  __syncthreads();
  s = sa[0]+sa[1]+sa[2]+sa[3]+sa[4]+sa[5];
  s2 = sb[0]+sb[1]+sb[2]+sb[3]+sb[4]+sb[5];
  float m = s*(1.f/DI);
  float var = s2*(1.f/DI) - m*m;
  float rstd = rsqrtf(var + 1e-5f);
  float v = (y - m)*rstd*og[d] + ob[d];
  float z = xz[((size_t)(b*LL + l))*(2*DI) + DI + d];
  a2[((size_t)(b*LL + l))*DI + d] = bf16r_(v * siluf_(z));
}

extern "C" void kernel_launch(void* const* d_in, const int* in_sizes, int n_in,
                              void* d_out, int out_size, void* d_ws, size_t ws_size,
                              hipStream_t stream) {
  (void)in_sizes; (void)n_in; (void)out_size; (void)ws_size;
  const float* x       = (const float*)d_in[0];
  const float* cpe1_w  = (const float*)d_in[1];
  const float* cpe1_b  = (const float*)d_in[2];
  const float* ln1_g   = (const float*)d_in[3];
  const float* ln1_b   = (const float*)d_in[4];
  const float* in_proj = (const float*)d_in[5];
  const float* conv_w  = (const float*)d_in[6];
  const float* conv_b  = (const float*)d_in[7];
  const float* x_proj  = (const float*)d_in[8];
  const float* dt_w    = (const float*)d_in[9];
  const float* dt_b    = (const float*)d_in[10];
  const float* A_logs  = (const float*)d_in[11];
  const float* Dsv     = (const float*)d_in[12];
  const float* onorm_g = (const float*)d_in[13];
  const float* onorm_b = (const float*)d_in[14];
  const float* out_proj= (const float*)d_in[15];
  const float* cpe2_w  = (const float*)d_in[16];
  const float* cpe2_b  = (const float*)d_in[17];
  const float* ln2_g   = (const float*)d_in[18];
  const float* ln2_b   = (const float*)d_in[19];
  const float* fc1_w   = (const float*)d_in[20];
  const float* fc1_b   = (const float*)d_in[21];
  const float* fc2_w   = (const float*)d_in[22];
  const float* fc2_b   = (const float*)d_in[23];
  float* out = (float*)d_out;
  float* wsf = (float*)d_ws;

  float* x1    = wsf;                        // 1,204,224 f
  float* xlnf  = x1 + 1204224;               // 1,204,224 f
  float* xz    = xlnf + 1204224;             // 4,816,896 f
  float* xc_l0 = xz + 4816896;               // 2,408,448 f  (B,L,Di) fp32
  float* xc_l1 = xc_l0 + 2408448;            // 2,408,448 f  (B,L1,Di) fp32
  float* ysbf  = xc_l1 + 2408448;            // 4,816,896 f = 9,633,792 bf16 (bk,L,Di)
  float* hendf = ysbf + 4816896;             // 2,408,448 f = 4,816,896 bf16 (bk,NCH,Di,16)
  float* sumdt = hendf + 2408448;            // 301,056 f
  float* xdblT = sumdt + 301056;             // 1,204,224 f
  unsigned short* wbf = (unsigned short*)(xdblT + 1204224); // 516,096 bf16
  unsigned short* wXhi = wbf + 516096;       // 73,728 bf16
  unsigned short* wXlo = wXhi + 73728;       // 73,728 bf16
  // aliases (lifetime-disjoint)
  unsigned short* xln  = (unsigned short*)xlnf;
  unsigned short* xln2 = (unsigned short*)xlnf;
  unsigned short* ysb  = (unsigned short*)ysbf;
  unsigned short* hend = (unsigned short*)hendf;
  unsigned short* a2   = (unsigned short*)xdblT;  // after scan2
  float* x2   = xc_l0;                            // after k_fuse
  float* x3   = xz;                               // after k_fuse
  unsigned short* hbuf = (unsigned short*)ysbf;   // after k_fuse
  unsigned short* wIn  = wbf;
  unsigned short* wOut = wbf + 147456;
  unsigned short* wF1  = wbf + 221184;
  unsigned short* wF2  = wbf + 368640;

  k_prep<<<2016+288, 256, 0, stream>>>(in_proj, out_proj, fc1_w, fc2_w, wbf, x_proj, wXhi, wXlo);
  k_dwln<<<BB*HHH*WWW, 192, 0, stream>>>(x, cpe1_w, cpe1_b, ln1_g, ln1_b, x1, xln, 1e-6f);
  k_gemm_mfma<128,EPI_NONE,0><<<dim3(768/64, BL/128), 256, 0, stream>>>(xln, wIn, nullptr, nullptr, xz, BL, 2*DI, CC);
  k_conv_xx<<<(BB*LL*DI+255)/256, 256, 0, stream>>>(xz, conv_w, conv_b, xc_l0, xc_l1);
  k_xgemm<<<dim3(3, BL/64), 256, 0, stream>>>(xc_l0, wXhi, wXlo, xdblT);
  k_scan<0><<<dim3(6, NCH, BB*KK), 64, 0, stream>>>(xc_l0, xc_l1, xdblT, dt_w, dt_b, A_logs, Dsv, hend, sumdt, ysb);
  k_scanmid<<<BB*KK*96, 64, 0, stream>>>(A_logs, sumdt, hend);
  k_scan<1><<<dim3(6, NCH, BB*KK), 64, 0, stream>>>(xc_l0, xc_l1, xdblT, dt_w, dt_b, A_logs, Dsv, hend, sumdt, ysb);
  k_fuse<<<BB*LL, 384, 0, stream>>>(ysb, xz, onorm_g, onorm_b, a2);
  k_gemm_mfma<64,EPI_RES,0><<<dim3(192/64, BL/64), 256, 0, stream>>>(a2, wOut, nullptr, x1, x2, BL, CC, DI);
  k_dwln<<<BB*HHH*WWW, 192, 0, stream>>>(x2, cpe2_w, cpe2_b, ln2_g, ln2_b, x3, xln2, 1e-6f);
  k_gemm_mfma<128,EPI_BIAS_GELU,1><<<dim3(768/64, BL/128), 256, 0, stream>>>(xln2, wF1, fc1_b, nullptr, hbuf, BL, HIDN, CC);
  k_gemm_mfma<64,EPI_BIAS_RES,0><<<dim3(192/64, BL/64), 256, 0, stream>>>(hbuf, wF2, fc2_b, x3, out, BL, CC, HIDN);
}

// Round 20
// 212.789 us; speedup vs baseline: 1.1245x; 1.0202x over previous
//
#include <hip/hip_runtime.h>
#include <math.h>

#define BB 2
#define HHH 56
#define WWW 56
#define CC 192
#define LL 3136
#define DI 384
#define KK 4
#define NN 16
#define RR 12
#define CP 44
#define HIDN 768
#define BL (BB*LL)
#define NCH 98   // chunks per sequence
#define CHL 32   // chunk length (98*32 = 3136)

typedef __attribute__((ext_vector_type(8))) short bf16x8;
typedef __attribute__((ext_vector_type(4))) float f32x4;

__device__ __forceinline__ float siluf_(float x){ return x/(1.f+__expf(-x)); }
__device__ __forceinline__ float geluf_(float x){ return 0.5f*x*(1.f+erff(x*0.70710678118654752f)); }
__device__ __forceinline__ unsigned short bf16r_(float x){
  unsigned int u = __float_as_uint(x);
  u += 0x7FFFu + ((u>>16)&1u);
  return (unsigned short)(u>>16);
}
__device__ __forceinline__ float bf2f_(unsigned short u){
  return __uint_as_float(((unsigned int)u)<<16);
}

// ---- fused depthwise 3x3 + residual + LayerNorm(192); tail blocks do weight prep ----
__global__ __launch_bounds__(192) void k_dwln(const float* __restrict__ in,
      const float* __restrict__ wgt, const float* __restrict__ bias,
      const float* __restrict__ g, const float* __restrict__ bta,
      float* __restrict__ xout, unsigned short* __restrict__ lnout, float eps,
      const float* __restrict__ p0, const float* __restrict__ p1,
      const float* __restrict__ p2, const float* __restrict__ p3,
      unsigned short* __restrict__ dst,
      const float* __restrict__ xp, unsigned short* __restrict__ wXhi,
      unsigned short* __restrict__ wXlo) {
  __shared__ float sa[3], sb[3];
  int pix = blockIdx.x;
  if (pix >= BB*HHH*WWW){
    // prep path: convert weights to bf16 / split x_proj
    int i = (pix - BB*HHH*WWW)*192 + threadIdx.x;
    if (i < 516096){
      if      (i < 147456) dst[i] = bf16r_(p0[i]);
      else if (i < 221184) dst[i] = bf16r_(p1[i-147456]);
      else if (i < 368640) dst[i] = bf16r_(p2[i-221184]);
      else                 dst[i] = bf16r_(p3[i-368640]);
    } else {
      int idx = i - 516096;
      if (idx < 192*384){
        int row = idx / 384, d = idx % 384;
        int k = row / 48, j = row % 48;
        float v = 0.f;
        if (j < 12) v = xp[(k*CP + j)*DI + d];
        else if (j >= 16) v = xp[(k*CP + (j-4))*DI + d];
        unsigned short hi = bf16r_(v);
        wXhi[idx] = hi;
        wXlo[idx] = bf16r_(v - bf2f_(hi));
      }
    }
    return;
  }
  int c = threadIdx.x;
  int w = pix % WWW, h = (pix/WWW) % HHH, b = pix/(WWW*HHH);
  float acc = bias[c];
  #pragma unroll
  for (int kh=0; kh<3; kh++){
    int hh = h + kh - 1; if (hh < 0 || hh >= HHH) continue;
    #pragma unroll
    for (int kw=0; kw<3; kw++){
      int ww = w + kw - 1; if (ww < 0 || ww >= WWW) continue;
      acc += in[((b*HHH+hh)*WWW+ww)*CC + c] * wgt[c*9 + kh*3 + kw];
    }
  }
  float v = in[(size_t)pix*CC + c] + acc;
  xout[(size_t)pix*CC + c] = v;
  float rs1 = v, rs2 = v*v;
  #pragma unroll
  for (int off=1; off<64; off<<=1){ rs1 += __shfl_xor(rs1,off); rs2 += __shfl_xor(rs2,off); }
  int wv = c >> 6;
  if ((c & 63) == 0){ sa[wv] = rs1; sb[wv] = rs2; }
  __syncthreads();
  rs1 = sa[0]+sa[1]+sa[2];
  rs2 = sb[0]+sb[1]+sb[2];
  float m = rs1*(1.f/192.f);
  float var = rs2*(1.f/192.f) - m*m;
  float rstd = rsqrtf(var + eps);
  lnout[(size_t)pix*CC + c] = bf16r_((v-m)*rstd*g[c] + bta[c]);
}

// ------- bf16 MFMA GEMM: out(MxN) = A(MxK)*W(NxK)^T; MT = M-tile (128 or 64) -------
// EPI_SPLITXZ: cols<DI -> fp32 xx (outp, ld=DI); cols>=DI -> bf16 z (zout, ld=DI)
enum { EPI_NONE=0, EPI_RES=1, EPI_BIAS_GELU=2, EPI_BIAS_RES=3, EPI_SPLITXZ=4 };

template<int MT, int EPI, int OUTBF>
__global__ __launch_bounds__(256) void k_gemm_mfma(const unsigned short* __restrict__ A,
      const unsigned short* __restrict__ W, const float* __restrict__ bias,
      const float* __restrict__ res, void* __restrict__ outp,
      unsigned short* __restrict__ zout, int M, int Nn, int Kk) {
  __shared__ unsigned short As[MT][40];
  __shared__ unsigned short Bs[64][40];
  constexpr int NI = (MT==128) ? 4 : 2;
  int tid = threadIdx.x;
  int m0 = blockIdx.y*MT, n0 = blockIdx.x*64;
  int wid = tid>>6, lane = tid&63;
  int wm = (MT==128) ? wid*32 : (wid&1)*32;
  int wn = (MT==128) ? 0 : (wid>>1)*32;
  int fr = lane&15, fk = (lane>>4)*8;
  f32x4 acc[2][NI];
  #pragma unroll
  for (int i=0;i<2;i++)
    #pragma unroll
    for (int j=0;j<NI;j++) acc[i][j] = (f32x4){0.f,0.f,0.f,0.f};
  int arow, ak;
  if (MT==128){ arow = tid>>1; ak = (tid&1)*16; }
  else        { arow = tid>>2; ak = (tid&3)*8;  }
  int wrow = tid>>2, wk = (tid&3)*8;
  const unsigned short* Ap = A + (size_t)(m0+arow)*Kk + ak;
  const unsigned short* Wp = W + (size_t)(n0+wrow)*Kk + wk;
  for (int k0=0; k0<Kk; k0+=32){
    __syncthreads();
    if (MT==128){
      uint4 av0 = *(const uint4*)(Ap + k0);
      uint4 av1 = *(const uint4*)(Ap + k0 + 8);
      *(uint4*)&As[arow][ak]   = av0;
      *(uint4*)&As[arow][ak+8] = av1;
    } else {
      *(uint4*)&As[arow][ak] = *(const uint4*)(Ap + k0);
    }
    *(uint4*)&Bs[wrow][wk] = *(const uint4*)(Wp + k0);
    __syncthreads();
    bf16x8 af[2], bfr[NI];
    #pragma unroll
    for (int mi=0;mi<2;mi++) af[mi] = *(const bf16x8*)&As[wm + mi*16 + fr][fk];
    #pragma unroll
    for (int ni=0;ni<NI;ni++) bfr[ni] = *(const bf16x8*)&Bs[wn + ni*16 + fr][fk];
    #pragma unroll
    for (int mi=0;mi<2;mi++)
      #pragma unroll
      for (int ni=0;ni<NI;ni++)
        acc[mi][ni] = __builtin_amdgcn_mfma_f32_16x16x32_bf16(af[mi], bfr[ni], acc[mi][ni], 0,0,0);
  }
  int rbase = (lane>>4)*4;
  #pragma unroll
  for (int mi=0;mi<2;mi++){
    #pragma unroll
    for (int ni=0;ni<NI;ni++){
      int col = n0 + wn + ni*16 + fr;
      float bv = (EPI==EPI_BIAS_GELU || EPI==EPI_BIAS_RES) ? bias[col] : 0.f;
      #pragma unroll
      for (int r=0;r<4;r++){
        int row = m0 + wm + mi*16 + rbase + r;
        float v = acc[mi][ni][r] + bv;
        if (EPI==EPI_BIAS_GELU) v = geluf_(v);
        if (EPI==EPI_RES || EPI==EPI_BIAS_RES) v += res[(size_t)row*Nn + col];
        if (EPI==EPI_SPLITXZ){
          if (col < DI) ((float*)outp)[(size_t)row*DI + col] = v;
          else zout[(size_t)row*DI + (col-DI)] = bf16r_(v);
        } else if (OUTBF) ((unsigned short*)outp)[(size_t)row*Nn + col] = bf16r_(v);
        else       ((float*)outp)[(size_t)row*Nn + col] = v;
      }
    }
  }
}

// ------- x_dbl split-bf16 GEMM: u_f32(BLx384) * wX(192x384)^T, scatter to records -------
__global__ __launch_bounds__(256) void k_xgemm(const float* __restrict__ uf,
      const unsigned short* __restrict__ wXhi, const unsigned short* __restrict__ wXlo,
      float* __restrict__ xdblT) {
  __shared__ unsigned short Ah[64][40];
  __shared__ unsigned short Al[64][40];
  __shared__ unsigned short Bh[64][40];
  __shared__ unsigned short Bl[64][40];
  int tid = threadIdx.x;
  int m0 = blockIdx.y*64, n0 = blockIdx.x*64;
  int wid = tid>>6, lane = tid&63;
  int fr = lane&15, fk = (lane>>4)*8;
  f32x4 acc[4];
  #pragma unroll
  for (int j=0;j<4;j++) acc[j] = (f32x4){0.f,0.f,0.f,0.f};
  int srow = tid>>2, sk = (tid&3)*8;
  const float* Ap = uf + (size_t)(m0+srow)*DI + sk;
  const unsigned short* Wh = wXhi + (size_t)(n0+srow)*DI + sk;
  const unsigned short* Wl = wXlo + (size_t)(n0+srow)*DI + sk;
  for (int k0=0; k0<DI; k0+=32){
    __syncthreads();
    float4 ua = *(const float4*)(Ap + k0);
    float4 ub = *(const float4*)(Ap + k0 + 4);
    uint4 wh = *(const uint4*)(Wh + k0);
    uint4 wl = *(const uint4*)(Wl + k0);
    float uv[8] = {ua.x,ua.y,ua.z,ua.w, ub.x,ub.y,ub.z,ub.w};
    #pragma unroll
    for (int j=0;j<8;j++){
      unsigned short hi = bf16r_(uv[j]);
      Ah[srow][sk+j] = hi;
      Al[srow][sk+j] = bf16r_(uv[j] - bf2f_(hi));
    }
    *(uint4*)&Bh[srow][sk] = wh;
    *(uint4*)&Bl[srow][sk] = wl;
    __syncthreads();
    bf16x8 ah = *(const bf16x8*)&Ah[wid*16 + fr][fk];
    bf16x8 al = *(const bf16x8*)&Al[wid*16 + fr][fk];
    #pragma unroll
    for (int ni=0;ni<4;ni++){
      bf16x8 bh = *(const bf16x8*)&Bh[ni*16 + fr][fk];
      bf16x8 bl = *(const bf16x8*)&Bl[ni*16 + fr][fk];
      acc[ni] = __builtin_amdgcn_mfma_f32_16x16x32_bf16(ah, bh, acc[ni], 0,0,0);
      acc[ni] = __builtin_amdgcn_mfma_f32_16x16x32_bf16(al, bh, acc[ni], 0,0,0);
      acc[ni] = __builtin_amdgcn_mfma_f32_16x16x32_bf16(ah, bl, acc[ni], 0,0,0);
    }
  }
  int rbase = (lane>>4)*4;
  #pragma unroll
  for (int ni=0;ni<4;ni++){
    int col = n0 + ni*16 + fr;
    int k = col / 48, j = col % 48;
    #pragma unroll
    for (int r=0;r<4;r++){
      int row = m0 + wid*16 + rbase + r;
      int b = row / LL, s = row % LL;
      int h = s / WWW, w2 = s % WWW;
      int l1 = w2*HHH + h;
      int lk = (k==0) ? s : (k==1) ? l1 : (k==2) ? (LL-1-s) : (LL-1-l1);
      xdblT[((size_t)((b*KK+k)*LL + lk))*48 + j] = acc[ni][r];
    }
  }
}

// ---- depthwise conv 3x3 + bias + SiLU on dense xx -> fp32 u in both sequence layouts ----
__global__ void k_conv_xx(const float* __restrict__ xx, const float* __restrict__ cw,
                          const float* __restrict__ cb, float* __restrict__ xc0,
                          float* __restrict__ xc1) {
  int idx = blockIdx.x*256 + threadIdx.x;
  if (idx >= BB*LL*DI) return;
  int d = idx % DI;
  int l = (idx / DI) % LL;
  int b = idx / (DI*LL);
  int h = l / WWW, w = l % WWW;
  float acc = cb[d];
  #pragma unroll
  for (int kh=0; kh<3; kh++){
    int hh = h + kh - 1; if (hh < 0 || hh >= HHH) continue;
    #pragma unroll
    for (int kw=0; kw<3; kw++){
      int ww2 = w + kw - 1; if (ww2 < 0 || ww2 >= WWW) continue;
      acc += xx[((size_t)(b*LL + hh*WWW + ww2))*DI + d] * cw[d*9 + kh*3 + kw];
    }
  }
  float v = siluf_(acc);
  xc0[idx] = v;
  xc1[((size_t)(b*LL + w*HHH + h))*DI + d] = v;
}

// ======== chunked selective scan: single-wave blocks, LDS-staged records (r13 form) ========
template<int PASS>
__global__ __launch_bounds__(64) void k_scan(const float* __restrict__ xc_l0,
        const float* __restrict__ xc_l1,
        const float* __restrict__ xdblT, const float* __restrict__ dtw, const float* __restrict__ dtb,
        const float* __restrict__ alogs, const float* __restrict__ Dsv,
        unsigned short* __restrict__ hend, float* __restrict__ sumdt, unsigned short* __restrict__ ysb) {
  __shared__ float recs[CHL*48];   // 6144 B: whole chunk's records
  int ch = blockIdx.y, bk = blockIdx.z;
  int b = bk >> 2, k = bk & 3;
  int lane = threadIdx.x;
  int d = blockIdx.x*64 + lane;
  int kd = k*DI + d;
  const float4* rg = (const float4*)(xdblT + ((size_t)bk*LL + ch*CHL)*48);
  float4* rs = (float4*)recs;
  #pragma unroll
  for (int j=0;j<6;j++) rs[lane + j*64] = rg[lane + j*64];
  float w[12];
  #pragma unroll
  for (int r=0;r<12;r++) w[r] = dtw[kd*12 + r];
  float biasd = dtb[kd];
  float Dd = (PASS==1) ? Dsv[kd] : 0.f;
  float An2[16];
  #pragma unroll
  for (int n=0;n<16;n++) An2[n] = -__expf(alogs[kd*16 + n]) * 1.44269504f;
  bool pw = true;
  #pragma unroll
  for (int n=1;n<16;n++) pw = pw && (fabsf(An2[n] - (float)(n+1)*An2[0]) <= 1e-3f*(float)(n+1)*fabsf(An2[0]));
  const float* usrc = (k & 1) ? xc_l1 : xc_l0;
  bool rev = (k >= 2);
  float h[16];
  size_t hb = ((size_t)(bk*NCH + ch)*DI + d)*16;
  if (PASS==0){
    #pragma unroll
    for (int n=0;n<16;n++) h[n]=0.f;
  } else {
    uint4 q0 = *(const uint4*)&hend[hb];
    uint4 q1 = *(const uint4*)&hend[hb+8];
    unsigned int qa[8] = {q0.x,q0.y,q0.z,q0.w, q1.x,q1.y,q1.z,q1.w};
    #pragma unroll
    for (int j=0;j<8;j++){
      h[2*j]   = bf2f_((unsigned short)(qa[j] & 0xffffu));
      h[2*j+1] = bf2f_((unsigned short)(qa[j] >> 16));
    }
  }
  __syncthreads();   // records staged
  float cum = 0.f;
  #pragma unroll 2
  for (int i=0;i<CHL;i++){
    int li = ch*CHL + i;
    int lsrc = rev ? (LL-1-li) : li;
    float uu = usrc[((size_t)(b*LL + lsrc))*DI + d];
    const float* rec = recs + i*48;
    float4 t0 = *(const float4*)(rec);
    float4 t1 = *(const float4*)(rec+4);
    float4 t2 = *(const float4*)(rec+8);
    float4 B0 = *(const float4*)(rec+16);
    float4 B1 = *(const float4*)(rec+20);
    float4 B2 = *(const float4*)(rec+24);
    float4 B3 = *(const float4*)(rec+28);
    float a0 = fmaf(t0.x,w[0], fmaf(t0.y,w[1], fmaf(t0.z,w[2], t0.w*w[3])));
    float a1 = fmaf(t1.x,w[4], fmaf(t1.y,w[5], fmaf(t1.z,w[6], t1.w*w[7])));
    float a2 = fmaf(t2.x,w[8], fmaf(t2.y,w[9], fmaf(t2.z,w[10], t2.w*w[11])));
    float a = biasd + a0 + (a1 + a2);
    float dt = 0.69314718f * log2f(1.f + exp2f(a*1.44269504f));
    float dtu = dt*uu;
    if (PASS==0) cum += dt;
    float dA[16];
    if (pw){
      float r1 = exp2f(dt*An2[0]);
      float r2 = r1*r1;
      float r3 = r2*r1;
      float r4 = r2*r2;
      float r8 = r4*r4;
      dA[0]=r1;     dA[1]=r2;     dA[2]=r3;     dA[3]=r4;
      dA[4]=r4*r1;  dA[5]=r4*r2;  dA[6]=r4*r3;  dA[7]=r8;
      dA[8]=r8*r1;  dA[9]=r8*r2;  dA[10]=r8*r3; dA[11]=r8*r4;
      dA[12]=r8*dA[4]; dA[13]=r8*dA[5]; dA[14]=r8*dA[6]; dA[15]=r8*r8;
    } else {
      #pragma unroll
      for (int n=0;n<16;n++) dA[n] = exp2f(dt*An2[n]);
    }
    float Bv[16] = {B0.x,B0.y,B0.z,B0.w, B1.x,B1.y,B1.z,B1.w,
                    B2.x,B2.y,B2.z,B2.w, B3.x,B3.y,B3.z,B3.w};
    #pragma unroll
    for (int n=0;n<16;n++) h[n] = fmaf(dA[n], h[n], dtu*Bv[n]);
    if (PASS==1){
      float4 C0 = *(const float4*)(rec+32);
      float4 C1 = *(const float4*)(rec+36);
      float4 C2 = *(const float4*)(rec+40);
      float4 C3 = *(const float4*)(rec+44);
      float y0 = fmaf(h[0], C0.x, fmaf(h[1], C0.y, fmaf(h[2], C0.z, h[3]*C0.w)));
      float y1 = fmaf(h[4], C1.x, fmaf(h[5], C1.y, fmaf(h[6], C1.z, h[7]*C1.w)));
      float y2 = fmaf(h[8], C2.x, fmaf(h[9], C2.y, fmaf(h[10],C2.z, h[11]*C2.w)));
      float y3 = fmaf(h[12],C3.x, fmaf(h[13],C3.y, fmaf(h[14],C3.z, h[15]*C3.w)));
      float y = fmaf(uu, Dd, (y0+y1)+(y2+y3));
      ysb[((size_t)(bk*LL + li))*DI + d] = bf16r_(y);
    }
  }
  if (PASS==0){
    unsigned int pk[8];
    #pragma unroll
    for (int j=0;j<8;j++)
      pk[j] = ((unsigned int)bf16r_(h[2*j+1])<<16) | (unsigned int)bf16r_(h[2*j]);
    *(uint4*)&hend[hb]   = make_uint4(pk[0],pk[1],pk[2],pk[3]);
    *(uint4*)&hend[hb+8] = make_uint4(pk[4],pk[5],pk[6],pk[7]);
    sumdt[(bk*NCH + ch)*DI + d] = cum;
  }
}

// S2: per (b,k,4d-block) wave: prefix over chunks; hend[c] <- incoming state H_{c-1} (bf16)
__global__ __launch_bounds__(64) void k_scanmid(const float* __restrict__ alogs,
        const float* __restrict__ sumdt, unsigned short* __restrict__ hend) {
  int bid = blockIdx.x;
  int dblk = bid % 96;
  int k = (bid/96) % KK;
  int b = bid/(96*KK);
  int lane = threadIdx.x;
  int d4 = lane>>4, n = lane&15;
  int d = dblk*4 + d4;
  int bk = b*KK + k;
  float Ac2 = -__expf(alogs[(k*DI+d)*16 + n]) * 1.44269504f;
  float H = 0.f;
  for (int c=0;c<NCH;c++){
    float sdt = sumdt[(bk*NCH + c)*DI + d];
    float aexp = exp2f(Ac2 * sdt);
    size_t idx = ((size_t)(bk*NCH + c)*DI + dblk*4)*16 + lane;
    float tmp = bf2f_(hend[idx]);
    hend[idx] = bf16r_(H);
    H = fmaf(aexp, H, tmp);
  }
}

// ----- fused combine + LN(Di) + silu(z bf16) gate -> a2 (B,L,Di) bf16 -----
__global__ __launch_bounds__(384) void k_fuse(const unsigned short* __restrict__ ysb,
      const unsigned short* __restrict__ zb, const float* __restrict__ og,
      const float* __restrict__ ob, unsigned short* __restrict__ a2) {
  __shared__ float sa[6], sb[6];
  int b = blockIdx.x / LL, l = blockIdx.x % LL;
  int d = threadIdx.x;
  int h_ = l / WWW, w_ = l % WWW;
  int l1 = w_*HHH + h_;
  float y = bf2f_(ysb[((size_t)((b*KK+0)*LL + l))*DI + d])
          + bf2f_(ysb[((size_t)((b*KK+1)*LL + l1))*DI + d])
          + bf2f_(ysb[((size_t)((b*KK+2)*LL + (LL-1-l)))*DI + d])
          + bf2f_(ysb[((size_t)((b*KK+3)*LL + (LL-1-l1)))*DI + d]);
  float s = y, s2 = y*y;
  #pragma unroll
  for (int off=1; off<64; off<<=1){ s += __shfl_xor(s,off); s2 += __shfl_xor(s2,off); }
  int wid = d >> 6;
  if ((d & 63) == 0){ sa[wid] = s; sb[wid] = s2; }
  __syncthreads();
  s = sa[0]+sa[1]+sa[2]+sa[3]+sa[4]+sa[5];
  s2 = sb[0]+sb[1]+sb[2]+sb[3]+sb[4]+sb[5];
  float m = s*(1.f/DI);
  float var = s2*(1.f/DI) - m*m;
  float rstd = rsqrtf(var + 1e-5f);
  float v = (y - m)*rstd*og[d] + ob[d];
  float z = bf2f_(zb[((size_t)(b*LL + l))*DI + d]);
  a2[((size_t)(b*LL + l))*DI + d] = bf16r_(v * siluf_(z));
}

extern "C" void kernel_launch(void* const* d_in, const int* in_sizes, int n_in,
                              void* d_out, int out_size, void* d_ws, size_t ws_size,
                              hipStream_t stream) {
  (void)in_sizes; (void)n_in; (void)out_size; (void)ws_size;
  const float* x       = (const float*)d_in[0];
  const float* cpe1_w  = (const float*)d_in[1];
  const float* cpe1_b  = (const float*)d_in[2];
  const float* ln1_g   = (const float*)d_in[3];
  const float* ln1_b   = (const float*)d_in[4];
  const float* in_proj = (const float*)d_in[5];
  const float* conv_w  = (const float*)d_in[6];
  const float* conv_b  = (const float*)d_in[7];
  const float* x_proj  = (const float*)d_in[8];
  const float* dt_w    = (const float*)d_in[9];
  const float* dt_b    = (const float*)d_in[10];
  const float* A_logs  = (const float*)d_in[11];
  const float* Dsv     = (const float*)d_in[12];
  const float* onorm_g = (const float*)d_in[13];
  const float* onorm_b = (const float*)d_in[14];
  const float* out_proj= (const float*)d_in[15];
  const float* cpe2_w  = (const float*)d_in[16];
  const float* cpe2_b  = (const float*)d_in[17];
  const float* ln2_g   = (const float*)d_in[18];
  const float* ln2_b   = (const float*)d_in[19];
  const float* fc1_w   = (const float*)d_in[20];
  const float* fc1_b   = (const float*)d_in[21];
  const float* fc2_w   = (const float*)d_in[22];
  const float* fc2_b   = (const float*)d_in[23];
  float* out = (float*)d_out;
  float* wsf = (float*)d_ws;

  float* x1    = wsf;                        // 1,204,224 f
  float* xlnf  = x1 + 1204224;               // 1,204,224 f
  float* xxbuf = xlnf + 1204224;             // 2,408,448 f  (B,L,Di) fp32 xx
  float* zbf   = xxbuf + 2408448;            // 1,204,224 f = 2,408,448 bf16 z
  float* xc_l0 = zbf + 1204224;              // 2,408,448 f  (B,L,Di) fp32
  float* xc_l1 = xc_l0 + 2408448;            // 2,408,448 f  (B,L1,Di) fp32
  float* ysbf  = xc_l1 + 2408448;            // 4,816,896 f = 9,633,792 bf16 (bk,L,Di)
  float* hendf = ysbf + 4816896;             // 2,408,448 f = 4,816,896 bf16
  float* sumdt = hendf + 2408448;            // 301,056 f
  float* xdblT = sumdt + 301056;             // 1,204,224 f
  unsigned short* wbf = (unsigned short*)(xdblT + 1204224); // 516,096 bf16
  unsigned short* wXhi = wbf + 516096;       // 73,728 bf16
  unsigned short* wXlo = wXhi + 73728;       // 73,728 bf16
  // aliases (lifetime-disjoint)
  unsigned short* xln  = (unsigned short*)xlnf;
  unsigned short* xln2 = (unsigned short*)xlnf;
  unsigned short* zb   = (unsigned short*)zbf;
  unsigned short* ysb  = (unsigned short*)ysbf;
  unsigned short* hend = (unsigned short*)hendf;
  unsigned short* a2   = (unsigned short*)xdblT;  // after scan2 reads xdblT
  float* x2   = xc_l0;                            // after scans
  float* x3   = xxbuf;                            // xx dead after conv_xx
  unsigned short* hbuf = (unsigned short*)ysbf;   // after k_fuse
  unsigned short* wIn  = wbf;
  unsigned short* wOut = wbf + 147456;
  unsigned short* wF1  = wbf + 221184;
  unsigned short* wF2  = wbf + 368640;

  const int NPIX = BB*HHH*WWW;                  // 6272
  const int PREPB = (516096 + 73728 + 191)/192; // prep items / 192
  k_dwln<<<NPIX + PREPB, 192, 0, stream>>>(x, cpe1_w, cpe1_b, ln1_g, ln1_b, x1, xln, 1e-6f,
        in_proj, out_proj, fc1_w, fc2_w, wbf, x_proj, wXhi, wXlo);
  k_gemm_mfma<128,EPI_SPLITXZ,0><<<dim3(768/64, BL/128), 256, 0, stream>>>(xln, wIn, nullptr, nullptr, xxbuf, zb, BL, 2*DI, CC);
  k_conv_xx<<<(BB*LL*DI+255)/256, 256, 0, stream>>>(xxbuf, conv_w, conv_b, xc_l0, xc_l1);
  k_xgemm<<<dim3(3, BL/64), 256, 0, stream>>>(xc_l0, wXhi, wXlo, xdblT);
  k_scan<0><<<dim3(6, NCH, BB*KK), 64, 0, stream>>>(xc_l0, xc_l1, xdblT, dt_w, dt_b, A_logs, Dsv, hend, sumdt, ysb);
  k_scanmid<<<BB*KK*96, 64, 0, stream>>>(A_logs, sumdt, hend);
  k_scan<1><<<dim3(6, NCH, BB*KK), 64, 0, stream>>>(xc_l0, xc_l1, xdblT, dt_w, dt_b, A_logs, Dsv, hend, sumdt, ysb);
  k_fuse<<<BB*LL, 384, 0, stream>>>(ysb, zb, onorm_g, onorm_b, a2);
  k_gemm_mfma<64,EPI_RES,0><<<dim3(192/64, BL/64), 256, 0, stream>>>(a2, wOut, nullptr, x1, x2, nullptr, BL, CC, DI);
  k_dwln<<<NPIX, 192, 0, stream>>>(x2, cpe2_w, cpe2_b, ln2_g, ln2_b, x3, xln2, 1e-6f,
        nullptr, nullptr, nullptr, nullptr, nullptr, nullptr, nullptr, nullptr);
  k_gemm_mfma<128,EPI_BIAS_GELU,1><<<dim3(768/64, BL/128), 256, 0, stream>>>(xln2, wF1, fc1_b, nullptr, hbuf, nullptr, BL, HIDN, CC);
  k_gemm_mfma<64,EPI_BIAS_RES,0><<<dim3(192/64, BL/64), 256, 0, stream>>>(hbuf, wF2, fc2_b, x3, out, nullptr, BL, CC, HIDN);
}

// Round 21
// 202.055 us; speedup vs baseline: 1.1842x; 1.0531x over previous
//
#include <hip/hip_runtime.h>
#include <math.h>

#define BB 2
#define HHH 56
#define WWW 56
#define CC 192
#define LL 3136
#define DI 384
#define KK 4
#define NN 16
#define RR 12
#define CP 44
#define HIDN 768
#define BL (BB*LL)
#define NCH 98   // chunks per sequence
#define CHL 32   // chunk length (98*32 = 3136)

typedef __attribute__((ext_vector_type(8))) short bf16x8;
typedef __attribute__((ext_vector_type(4))) float f32x4;

__device__ __forceinline__ float siluf_(float x){ return x/(1.f+__expf(-x)); }
__device__ __forceinline__ float geluf_(float x){ return 0.5f*x*(1.f+erff(x*0.70710678118654752f)); }
__device__ __forceinline__ unsigned short bf16r_(float x){
  unsigned int u = __float_as_uint(x);
  u += 0x7FFFu + ((u>>16)&1u);
  return (unsigned short)(u>>16);
}
__device__ __forceinline__ float bf2f_(unsigned short u){
  return __uint_as_float(((unsigned int)u)<<16);
}

// ---- fused depthwise 3x3 + residual + LayerNorm(192); tail blocks do weight prep ----
__global__ __launch_bounds__(192) void k_dwln(const float* __restrict__ in,
      const float* __restrict__ wgt, const float* __restrict__ bias,
      const float* __restrict__ g, const float* __restrict__ bta,
      float* __restrict__ xout, unsigned short* __restrict__ lnout, float eps,
      const float* __restrict__ p0, const float* __restrict__ p1,
      const float* __restrict__ p2, const float* __restrict__ p3,
      unsigned short* __restrict__ dst,
      const float* __restrict__ xp, unsigned short* __restrict__ wXhi,
      unsigned short* __restrict__ wXlo) {
  __shared__ float sa[3], sb[3];
  int pix = blockIdx.x;
  if (pix >= BB*HHH*WWW){
    int i = (pix - BB*HHH*WWW)*192 + threadIdx.x;
    if (i < 516096){
      if      (i < 147456) dst[i] = bf16r_(p0[i]);
      else if (i < 221184) dst[i] = bf16r_(p1[i-147456]);
      else if (i < 368640) dst[i] = bf16r_(p2[i-221184]);
      else                 dst[i] = bf16r_(p3[i-368640]);
    } else {
      int idx = i - 516096;
      if (idx < 192*384){
        int row = idx / 384, d = idx % 384;
        int k = row / 48, j = row % 48;
        float v = 0.f;
        if (j < 12) v = xp[(k*CP + j)*DI + d];
        else if (j >= 16) v = xp[(k*CP + (j-4))*DI + d];
        unsigned short hi = bf16r_(v);
        wXhi[idx] = hi;
        wXlo[idx] = bf16r_(v - bf2f_(hi));
      }
    }
    return;
  }
  int c = threadIdx.x;
  int w = pix % WWW, h = (pix/WWW) % HHH, b = pix/(WWW*HHH);
  float acc = bias[c];
  #pragma unroll
  for (int kh=0; kh<3; kh++){
    int hh = h + kh - 1; if (hh < 0 || hh >= HHH) continue;
    #pragma unroll
    for (int kw=0; kw<3; kw++){
      int ww = w + kw - 1; if (ww < 0 || ww >= WWW) continue;
      acc += in[((b*HHH+hh)*WWW+ww)*CC + c] * wgt[c*9 + kh*3 + kw];
    }
  }
  float v = in[(size_t)pix*CC + c] + acc;
  xout[(size_t)pix*CC + c] = v;
  float rs1 = v, rs2 = v*v;
  #pragma unroll
  for (int off=1; off<64; off<<=1){ rs1 += __shfl_xor(rs1,off); rs2 += __shfl_xor(rs2,off); }
  int wv = c >> 6;
  if ((c & 63) == 0){ sa[wv] = rs1; sb[wv] = rs2; }
  __syncthreads();
  rs1 = sa[0]+sa[1]+sa[2];
  rs2 = sb[0]+sb[1]+sb[2];
  float m = rs1*(1.f/192.f);
  float var = rs2*(1.f/192.f) - m*m;
  float rstd = rsqrtf(var + eps);
  lnout[(size_t)pix*CC + c] = bf16r_((v-m)*rstd*g[c] + bta[c]);
}

// ------- bf16 MFMA GEMM: out(MxN) = A(MxK)*W(NxK)^T; MT = M-tile (128 or 64) -------
// EPI_SPLITXZ: cols<DI -> fp32 xx (outp, ld=DI); cols>=DI -> bf16 z (zout, ld=DI)
enum { EPI_NONE=0, EPI_RES=1, EPI_BIAS_GELU=2, EPI_BIAS_RES=3, EPI_SPLITXZ=4 };

template<int MT, int EPI, int OUTBF>
__global__ __launch_bounds__(256) void k_gemm_mfma(const unsigned short* __restrict__ A,
      const unsigned short* __restrict__ W, const float* __restrict__ bias,
      const float* __restrict__ res, void* __restrict__ outp,
      unsigned short* __restrict__ zout, int M, int Nn, int Kk) {
  __shared__ unsigned short As[MT][40];
  __shared__ unsigned short Bs[64][40];
  constexpr int NI = (MT==128) ? 4 : 2;
  int tid = threadIdx.x;
  int m0 = blockIdx.y*MT, n0 = blockIdx.x*64;
  int wid = tid>>6, lane = tid&63;
  int wm = (MT==128) ? wid*32 : (wid&1)*32;
  int wn = (MT==128) ? 0 : (wid>>1)*32;
  int fr = lane&15, fk = (lane>>4)*8;
  f32x4 acc[2][NI];
  #pragma unroll
  for (int i=0;i<2;i++)
    #pragma unroll
    for (int j=0;j<NI;j++) acc[i][j] = (f32x4){0.f,0.f,0.f,0.f};
  int arow, ak;
  if (MT==128){ arow = tid>>1; ak = (tid&1)*16; }
  else        { arow = tid>>2; ak = (tid&3)*8;  }
  int wrow = tid>>2, wk = (tid&3)*8;
  const unsigned short* Ap = A + (size_t)(m0+arow)*Kk + ak;
  const unsigned short* Wp = W + (size_t)(n0+wrow)*Kk + wk;
  for (int k0=0; k0<Kk; k0+=32){
    __syncthreads();
    if (MT==128){
      uint4 av0 = *(const uint4*)(Ap + k0);
      uint4 av1 = *(const uint4*)(Ap + k0 + 8);
      *(uint4*)&As[arow][ak]   = av0;
      *(uint4*)&As[arow][ak+8] = av1;
    } else {
      *(uint4*)&As[arow][ak] = *(const uint4*)(Ap + k0);
    }
    *(uint4*)&Bs[wrow][wk] = *(const uint4*)(Wp + k0);
    __syncthreads();
    bf16x8 af[2], bfr[NI];
    #pragma unroll
    for (int mi=0;mi<2;mi++) af[mi] = *(const bf16x8*)&As[wm + mi*16 + fr][fk];
    #pragma unroll
    for (int ni=0;ni<NI;ni++) bfr[ni] = *(const bf16x8*)&Bs[wn + ni*16 + fr][fk];
    #pragma unroll
    for (int mi=0;mi<2;mi++)
      #pragma unroll
      for (int ni=0;ni<NI;ni++)
        acc[mi][ni] = __builtin_amdgcn_mfma_f32_16x16x32_bf16(af[mi], bfr[ni], acc[mi][ni], 0,0,0);
  }
  int rbase = (lane>>4)*4;
  #pragma unroll
  for (int mi=0;mi<2;mi++){
    #pragma unroll
    for (int ni=0;ni<NI;ni++){
      int col = n0 + wn + ni*16 + fr;
      float bv = (EPI==EPI_BIAS_GELU || EPI==EPI_BIAS_RES) ? bias[col] : 0.f;
      #pragma unroll
      for (int r=0;r<4;r++){
        int row = m0 + wm + mi*16 + rbase + r;
        float v = acc[mi][ni][r] + bv;
        if (EPI==EPI_BIAS_GELU) v = geluf_(v);
        if (EPI==EPI_RES || EPI==EPI_BIAS_RES) v += res[(size_t)row*Nn + col];
        if (EPI==EPI_SPLITXZ){
          if (col < DI) ((float*)outp)[(size_t)row*DI + col] = v;
          else zout[(size_t)row*DI + (col-DI)] = bf16r_(v);
        } else if (OUTBF) ((unsigned short*)outp)[(size_t)row*Nn + col] = bf16r_(v);
        else       ((float*)outp)[(size_t)row*Nn + col] = v;
      }
    }
  }
}

// ------- x_dbl split-bf16 GEMM: u_f32(BLx384) * wX(192x384)^T, scatter to records -------
__global__ __launch_bounds__(256) void k_xgemm(const float* __restrict__ uf,
      const unsigned short* __restrict__ wXhi, const unsigned short* __restrict__ wXlo,
      float* __restrict__ xdblT) {
  __shared__ unsigned short Ah[64][40];
  __shared__ unsigned short Al[64][40];
  __shared__ unsigned short Bh[64][40];
  __shared__ unsigned short Bl[64][40];
  int tid = threadIdx.x;
  int m0 = blockIdx.y*64, n0 = blockIdx.x*64;
  int wid = tid>>6, lane = tid&63;
  int fr = lane&15, fk = (lane>>4)*8;
  f32x4 acc[4];
  #pragma unroll
  for (int j=0;j<4;j++) acc[j] = (f32x4){0.f,0.f,0.f,0.f};
  int srow = tid>>2, sk = (tid&3)*8;
  const float* Ap = uf + (size_t)(m0+srow)*DI + sk;
  const unsigned short* Wh = wXhi + (size_t)(n0+srow)*DI + sk;
  const unsigned short* Wl = wXlo + (size_t)(n0+srow)*DI + sk;
  for (int k0=0; k0<DI; k0+=32){
    __syncthreads();
    float4 ua = *(const float4*)(Ap + k0);
    float4 ub = *(const float4*)(Ap + k0 + 4);
    uint4 wh = *(const uint4*)(Wh + k0);
    uint4 wl = *(const uint4*)(Wl + k0);
    float uv[8] = {ua.x,ua.y,ua.z,ua.w, ub.x,ub.y,ub.z,ub.w};
    #pragma unroll
    for (int j=0;j<8;j++){
      unsigned short hi = bf16r_(uv[j]);
      Ah[srow][sk+j] = hi;
      Al[srow][sk+j] = bf16r_(uv[j] - bf2f_(hi));
    }
    *(uint4*)&Bh[srow][sk] = wh;
    *(uint4*)&Bl[srow][sk] = wl;
    __syncthreads();
    bf16x8 ah = *(const bf16x8*)&Ah[wid*16 + fr][fk];
    bf16x8 al = *(const bf16x8*)&Al[wid*16 + fr][fk];
    #pragma unroll
    for (int ni=0;ni<4;ni++){
      bf16x8 bh = *(const bf16x8*)&Bh[ni*16 + fr][fk];
      bf16x8 bl = *(const bf16x8*)&Bl[ni*16 + fr][fk];
      acc[ni] = __builtin_amdgcn_mfma_f32_16x16x32_bf16(ah, bh, acc[ni], 0,0,0);
      acc[ni] = __builtin_amdgcn_mfma_f32_16x16x32_bf16(al, bh, acc[ni], 0,0,0);
      acc[ni] = __builtin_amdgcn_mfma_f32_16x16x32_bf16(ah, bl, acc[ni], 0,0,0);
    }
  }
  int rbase = (lane>>4)*4;
  #pragma unroll
  for (int ni=0;ni<4;ni++){
    int col = n0 + ni*16 + fr;
    int k = col / 48, j = col % 48;
    #pragma unroll
    for (int r=0;r<4;r++){
      int row = m0 + wid*16 + rbase + r;
      int b = row / LL, s = row % LL;
      int h = s / WWW, w2 = s % WWW;
      int l1 = w2*HHH + h;
      int lk = (k==0) ? s : (k==1) ? l1 : (k==2) ? (LL-1-s) : (LL-1-l1);
      xdblT[((size_t)((b*KK+k)*LL + lk))*48 + j] = acc[ni][r];
    }
  }
}

// ---- depthwise conv 3x3 + bias + SiLU on dense xx, float4-vectorized (4 d per thread) ----
__global__ void k_conv_xx(const float* __restrict__ xx, const float* __restrict__ cw,
                          const float* __restrict__ cb, float* __restrict__ xc0,
                          float* __restrict__ xc1) {
  int idx4 = blockIdx.x*256 + threadIdx.x;
  const int D4 = DI/4;
  if (idx4 >= BB*LL*D4) return;
  int d4 = (idx4 % D4)*4;
  int l  = (idx4 / D4) % LL;
  int b  = idx4 / (D4*LL);
  int h = l / WWW, w = l % WWW;
  float wv[4][9];
  #pragma unroll
  for (int j=0;j<4;j++)
    #pragma unroll
    for (int t=0;t<9;t++) wv[j][t] = cw[(d4+j)*9 + t];
  float4 cbv = *(const float4*)&cb[d4];
  float a0=cbv.x, a1=cbv.y, a2=cbv.z, a3=cbv.w;
  #pragma unroll
  for (int kh=0; kh<3; kh++){
    int hh = h + kh - 1; if (hh < 0 || hh >= HHH) continue;
    #pragma unroll
    for (int kw=0; kw<3; kw++){
      int ww2 = w + kw - 1; if (ww2 < 0 || ww2 >= WWW) continue;
      float4 v = *(const float4*)&xx[((size_t)(b*LL + hh*WWW + ww2))*DI + d4];
      int t = kh*3 + kw;
      a0 = fmaf(v.x, wv[0][t], a0);
      a1 = fmaf(v.y, wv[1][t], a1);
      a2 = fmaf(v.z, wv[2][t], a2);
      a3 = fmaf(v.w, wv[3][t], a3);
    }
  }
  float4 o = make_float4(siluf_(a0), siluf_(a1), siluf_(a2), siluf_(a3));
  *(float4*)&xc0[((size_t)(b*LL + l))*DI + d4] = o;
  *(float4*)&xc1[((size_t)(b*LL + w*HHH + h))*DI + d4] = o;
}

// ======== chunked selective scan: single-wave blocks, LDS-staged records (r13 form) ========
template<int PASS>
__global__ __launch_bounds__(64) void k_scan(const float* __restrict__ xc_l0,
        const float* __restrict__ xc_l1,
        const float* __restrict__ xdblT, const float* __restrict__ dtw, const float* __restrict__ dtb,
        const float* __restrict__ alogs, const float* __restrict__ Dsv,
        unsigned short* __restrict__ hend, float* __restrict__ sumdt, unsigned short* __restrict__ ysb) {
  __shared__ float recs[CHL*48];   // 6144 B: whole chunk's records
  int ch = blockIdx.y, bk = blockIdx.z;
  int b = bk >> 2, k = bk & 3;
  int lane = threadIdx.x;
  int d = blockIdx.x*64 + lane;
  int kd = k*DI + d;
  const float4* rg = (const float4*)(xdblT + ((size_t)bk*LL + ch*CHL)*48);
  float4* rs = (float4*)recs;
  #pragma unroll
  for (int j=0;j<6;j++) rs[lane + j*64] = rg[lane + j*64];
  float w[12];
  #pragma unroll
  for (int r=0;r<12;r++) w[r] = dtw[kd*12 + r];
  float biasd = dtb[kd];
  float Dd = (PASS==1) ? Dsv[kd] : 0.f;
  float An2[16];
  #pragma unroll
  for (int n=0;n<16;n++) An2[n] = -__expf(alogs[kd*16 + n]) * 1.44269504f;
  bool pw = true;
  #pragma unroll
  for (int n=1;n<16;n++) pw = pw && (fabsf(An2[n] - (float)(n+1)*An2[0]) <= 1e-3f*(float)(n+1)*fabsf(An2[0]));
  const float* usrc = (k & 1) ? xc_l1 : xc_l0;
  bool rev = (k >= 2);
  float h[16];
  size_t hb = ((size_t)(bk*NCH + ch)*DI + d)*16;
  if (PASS==0){
    #pragma unroll
    for (int n=0;n<16;n++) h[n]=0.f;
  } else {
    uint4 q0 = *(const uint4*)&hend[hb];
    uint4 q1 = *(const uint4*)&hend[hb+8];
    unsigned int qa[8] = {q0.x,q0.y,q0.z,q0.w, q1.x,q1.y,q1.z,q1.w};
    #pragma unroll
    for (int j=0;j<8;j++){
      h[2*j]   = bf2f_((unsigned short)(qa[j] & 0xffffu));
      h[2*j+1] = bf2f_((unsigned short)(qa[j] >> 16));
    }
  }
  __syncthreads();   // records staged
  float cum = 0.f;
  #pragma unroll 2
  for (int i=0;i<CHL;i++){
    int li = ch*CHL + i;
    int lsrc = rev ? (LL-1-li) : li;
    float uu = usrc[((size_t)(b*LL + lsrc))*DI + d];
    const float* rec = recs + i*48;
    float4 t0 = *(const float4*)(rec);
    float4 t1 = *(const float4*)(rec+4);
    float4 t2 = *(const float4*)(rec+8);
    float4 B0 = *(const float4*)(rec+16);
    float4 B1 = *(const float4*)(rec+20);
    float4 B2 = *(const float4*)(rec+24);
    float4 B3 = *(const float4*)(rec+28);
    float a0 = fmaf(t0.x,w[0], fmaf(t0.y,w[1], fmaf(t0.z,w[2], t0.w*w[3])));
    float a1 = fmaf(t1.x,w[4], fmaf(t1.y,w[5], fmaf(t1.z,w[6], t1.w*w[7])));
    float a2 = fmaf(t2.x,w[8], fmaf(t2.y,w[9], fmaf(t2.z,w[10], t2.w*w[11])));
    float a = biasd + a0 + (a1 + a2);
    float dt = 0.69314718f * log2f(1.f + exp2f(a*1.44269504f));
    float dtu = dt*uu;
    if (PASS==0) cum += dt;
    float dA[16];
    if (pw){
      float r1 = exp2f(dt*An2[0]);
      float r2 = r1*r1;
      float r3 = r2*r1;
      float r4 = r2*r2;
      float r8 = r4*r4;
      dA[0]=r1;     dA[1]=r2;     dA[2]=r3;     dA[3]=r4;
      dA[4]=r4*r1;  dA[5]=r4*r2;  dA[6]=r4*r3;  dA[7]=r8;
      dA[8]=r8*r1;  dA[9]=r8*r2;  dA[10]=r8*r3; dA[11]=r8*r4;
      dA[12]=r8*dA[4]; dA[13]=r8*dA[5]; dA[14]=r8*dA[6]; dA[15]=r8*r8;
    } else {
      #pragma unroll
      for (int n=0;n<16;n++) dA[n] = exp2f(dt*An2[n]);
    }
    float Bv[16] = {B0.x,B0.y,B0.z,B0.w, B1.x,B1.y,B1.z,B1.w,
                    B2.x,B2.y,B2.z,B2.w, B3.x,B3.y,B3.z,B3.w};
    #pragma unroll
    for (int n=0;n<16;n++) h[n] = fmaf(dA[n], h[n], dtu*Bv[n]);
    if (PASS==1){
      float4 C0 = *(const float4*)(rec+32);
      float4 C1 = *(const float4*)(rec+36);
      float4 C2 = *(const float4*)(rec+40);
      float4 C3 = *(const float4*)(rec+44);
      float y0 = fmaf(h[0], C0.x, fmaf(h[1], C0.y, fmaf(h[2], C0.z, h[3]*C0.w)));
      float y1 = fmaf(h[4], C1.x, fmaf(h[5], C1.y, fmaf(h[6], C1.z, h[7]*C1.w)));
      float y2 = fmaf(h[8], C2.x, fmaf(h[9], C2.y, fmaf(h[10],C2.z, h[11]*C2.w)));
      float y3 = fmaf(h[12],C3.x, fmaf(h[13],C3.y, fmaf(h[14],C3.z, h[15]*C3.w)));
      float y = fmaf(uu, Dd, (y0+y1)+(y2+y3));
      ysb[((size_t)(bk*LL + li))*DI + d] = bf16r_(y);
    }
  }
  if (PASS==0){
    unsigned int pk[8];
    #pragma unroll
    for (int j=0;j<8;j++)
      pk[j] = ((unsigned int)bf16r_(h[2*j+1])<<16) | (unsigned int)bf16r_(h[2*j]);
    *(uint4*)&hend[hb]   = make_uint4(pk[0],pk[1],pk[2],pk[3]);
    *(uint4*)&hend[hb+8] = make_uint4(pk[4],pk[5],pk[6],pk[7]);
    sumdt[(bk*NCH + ch)*DI + d] = cum;
  }
}

// S2: per (b,k,4d-block) wave: prefix over chunks; hend[c] <- incoming state H_{c-1} (bf16)
__global__ __launch_bounds__(64) void k_scanmid(const float* __restrict__ alogs,
        const float* __restrict__ sumdt, unsigned short* __restrict__ hend) {
  int bid = blockIdx.x;
  int dblk = bid % 96;
  int k = (bid/96) % KK;
  int b = bid/(96*KK);
  int lane = threadIdx.x;
  int d4 = lane>>4, n = lane&15;
  int d = dblk*4 + d4;
  int bk = b*KK + k;
  float Ac2 = -__expf(alogs[(k*DI+d)*16 + n]) * 1.44269504f;
  float H = 0.f;
  for (int c=0;c<NCH;c++){
    float sdt = sumdt[(bk*NCH + c)*DI + d];
    float aexp = exp2f(Ac2 * sdt);
    size_t idx = ((size_t)(bk*NCH + c)*DI + dblk*4)*16 + lane;
    float tmp = bf2f_(hend[idx]);
    hend[idx] = bf16r_(H);
    H = fmaf(aexp, H, tmp);
  }
}

// ----- fused combine + LN(Di) + silu(z) gate, 2 elems/thread -> a2 (B,L,Di) bf16 -----
__global__ __launch_bounds__(192) void k_fuse(const unsigned short* __restrict__ ysb,
      const unsigned short* __restrict__ zb, const float* __restrict__ og,
      const float* __restrict__ ob, unsigned short* __restrict__ a2) {
  __shared__ float sa[3], sb[3];
  int b = blockIdx.x / LL, l = blockIdx.x % LL;
  int d2 = threadIdx.x*2;
  int h_ = l / WWW, w_ = l % WWW;
  int l1 = w_*HHH + h_;
  unsigned int u0 = *(const unsigned int*)&ysb[((size_t)((b*KK+0)*LL + l))*DI + d2];
  unsigned int u1 = *(const unsigned int*)&ysb[((size_t)((b*KK+1)*LL + l1))*DI + d2];
  unsigned int u2 = *(const unsigned int*)&ysb[((size_t)((b*KK+2)*LL + (LL-1-l)))*DI + d2];
  unsigned int u3 = *(const unsigned int*)&ysb[((size_t)((b*KK+3)*LL + (LL-1-l1)))*DI + d2];
  float ya = bf2f_((unsigned short)(u0&0xffffu)) + bf2f_((unsigned short)(u1&0xffffu))
           + bf2f_((unsigned short)(u2&0xffffu)) + bf2f_((unsigned short)(u3&0xffffu));
  float yb = bf2f_((unsigned short)(u0>>16)) + bf2f_((unsigned short)(u1>>16))
           + bf2f_((unsigned short)(u2>>16)) + bf2f_((unsigned short)(u3>>16));
  float s = ya+yb, s2 = ya*ya+yb*yb;
  #pragma unroll
  for (int off=1; off<64; off<<=1){ s += __shfl_xor(s,off); s2 += __shfl_xor(s2,off); }
  int wid = threadIdx.x >> 6;
  if ((threadIdx.x & 63) == 0){ sa[wid] = s; sb[wid] = s2; }
  __syncthreads();
  s = sa[0]+sa[1]+sa[2];
  s2 = sb[0]+sb[1]+sb[2];
  float m = s*(1.f/DI);
  float var = s2*(1.f/DI) - m*m;
  float rstd = rsqrtf(var + 1e-5f);
  unsigned int zu = *(const unsigned int*)&zb[((size_t)(b*LL + l))*DI + d2];
  float za = bf2f_((unsigned short)(zu&0xffffu));
  float zc = bf2f_((unsigned short)(zu>>16));
  float va = ((ya - m)*rstd*og[d2]   + ob[d2])   * siluf_(za);
  float vb = ((yb - m)*rstd*og[d2+1] + ob[d2+1]) * siluf_(zc);
  unsigned int pk = ((unsigned int)bf16r_(vb)<<16) | (unsigned int)bf16r_(va);
  *(unsigned int*)&a2[((size_t)(b*LL + l))*DI + d2] = pk;
}

extern "C" void kernel_launch(void* const* d_in, const int* in_sizes, int n_in,
                              void* d_out, int out_size, void* d_ws, size_t ws_size,
                              hipStream_t stream) {
  (void)in_sizes; (void)n_in; (void)out_size; (void)ws_size;
  const float* x       = (const float*)d_in[0];
  const float* cpe1_w  = (const float*)d_in[1];
  const float* cpe1_b  = (const float*)d_in[2];
  const float* ln1_g   = (const float*)d_in[3];
  const float* ln1_b   = (const float*)d_in[4];
  const float* in_proj = (const float*)d_in[5];
  const float* conv_w  = (const float*)d_in[6];
  const float* conv_b  = (const float*)d_in[7];
  const float* x_proj  = (const float*)d_in[8];
  const float* dt_w    = (const float*)d_in[9];
  const float* dt_b    = (const float*)d_in[10];
  const float* A_logs  = (const float*)d_in[11];
  const float* Dsv     = (const float*)d_in[12];
  const float* onorm_g = (const float*)d_in[13];
  const float* onorm_b = (const float*)d_in[14];
  const float* out_proj= (const float*)d_in[15];
  const float* cpe2_w  = (const float*)d_in[16];
  const float* cpe2_b  = (const float*)d_in[17];
  const float* ln2_g   = (const float*)d_in[18];
  const float* ln2_b   = (const float*)d_in[19];
  const float* fc1_w   = (const float*)d_in[20];
  const float* fc1_b   = (const float*)d_in[21];
  const float* fc2_w   = (const float*)d_in[22];
  const float* fc2_b   = (const float*)d_in[23];
  float* out = (float*)d_out;
  float* wsf = (float*)d_ws;

  float* x1    = wsf;                        // 1,204,224 f
  float* xlnf  = x1 + 1204224;               // 1,204,224 f
  float* xxbuf = xlnf + 1204224;             // 2,408,448 f  (B,L,Di) fp32 xx
  float* zbf   = xxbuf + 2408448;            // 1,204,224 f = 2,408,448 bf16 z
  float* xc_l0 = zbf + 1204224;              // 2,408,448 f  (B,L,Di) fp32
  float* xc_l1 = xc_l0 + 2408448;            // 2,408,448 f  (B,L1,Di) fp32
  float* ysbf  = xc_l1 + 2408448;            // 4,816,896 f = 9,633,792 bf16 (bk,L,Di)
  float* hendf = ysbf + 4816896;             // 2,408,448 f = 4,816,896 bf16
  float* sumdt = hendf + 2408448;            // 301,056 f
  float* xdblT = sumdt + 301056;             // 1,204,224 f
  unsigned short* wbf = (unsigned short*)(xdblT + 1204224); // 516,096 bf16
  unsigned short* wXhi = wbf + 516096;       // 73,728 bf16
  unsigned short* wXlo = wXhi + 73728;       // 73,728 bf16
  // aliases (lifetime-disjoint)
  unsigned short* xln  = (unsigned short*)xlnf;
  unsigned short* xln2 = (unsigned short*)xlnf;
  unsigned short* zb   = (unsigned short*)zbf;
  unsigned short* ysb  = (unsigned short*)ysbf;
  unsigned short* hend = (unsigned short*)hendf;
  unsigned short* a2   = (unsigned short*)xdblT;  // after scan2 reads xdblT
  float* x2   = xc_l0;                            // after scans
  float* x3   = xxbuf;                            // xx dead after conv_xx
  unsigned short* hbuf = (unsigned short*)ysbf;   // after k_fuse
  unsigned short* wIn  = wbf;
  unsigned short* wOut = wbf + 147456;
  unsigned short* wF1  = wbf + 221184;
  unsigned short* wF2  = wbf + 368640;

  const int NPIX = BB*HHH*WWW;                  // 6272
  const int PREPB = (516096 + 73728 + 191)/192; // prep items / 192
  k_dwln<<<NPIX + PREPB, 192, 0, stream>>>(x, cpe1_w, cpe1_b, ln1_g, ln1_b, x1, xln, 1e-6f,
        in_proj, out_proj, fc1_w, fc2_w, wbf, x_proj, wXhi, wXlo);
  k_gemm_mfma<128,EPI_SPLITXZ,0><<<dim3(768/64, BL/128), 256, 0, stream>>>(xln, wIn, nullptr, nullptr, xxbuf, zb, BL, 2*DI, CC);
  k_conv_xx<<<(BB*LL*(DI/4)+255)/256, 256, 0, stream>>>(xxbuf, conv_w, conv_b, xc_l0, xc_l1);
  k_xgemm<<<dim3(3, BL/64), 256, 0, stream>>>(xc_l0, wXhi, wXlo, xdblT);
  k_scan<0><<<dim3(6, NCH, BB*KK), 64, 0, stream>>>(xc_l0, xc_l1, xdblT, dt_w, dt_b, A_logs, Dsv, hend, sumdt, ysb);
  k_scanmid<<<BB*KK*96, 64, 0, stream>>>(A_logs, sumdt, hend);
  k_scan<1><<<dim3(6, NCH, BB*KK), 64, 0, stream>>>(xc_l0, xc_l1, xdblT, dt_w, dt_b, A_logs, Dsv, hend, sumdt, ysb);
  k_fuse<<<BB*LL, 192, 0, stream>>>(ysb, zb, onorm_g, onorm_b, a2);
  k_gemm_mfma<64,EPI_RES,0><<<dim3(192/64, BL/64), 256, 0, stream>>>(a2, wOut, nullptr, x1, x2, nullptr, BL, CC, DI);
  k_dwln<<<NPIX, 192, 0, stream>>>(x2, cpe2_w, cpe2_b, ln2_g, ln2_b, x3, xln2, 1e-6f,
        nullptr, nullptr, nullptr, nullptr, nullptr, nullptr, nullptr, nullptr);
  k_gemm_mfma<128,EPI_BIAS_GELU,1><<<dim3(768/64, BL/128), 256, 0, stream>>>(xln2, wF1, fc1_b, nullptr, hbuf, nullptr, BL, HIDN, CC);
  k_gemm_mfma<64,EPI_BIAS_RES,0><<<dim3(192/64, BL/64), 256, 0, stream>>>(hbuf, wF2, fc2_b, x3, out, nullptr, BL, CC, HIDN);
}